// Round 1
// baseline (1223.178 us; speedup 1.0000x reference)
//
#include <hip/hip_runtime.h>
#include <hip/hip_bf16.h>

#define DEV __device__ __forceinline__

typedef unsigned short u16;
typedef short short8 __attribute__((ext_vector_type(8)));
typedef float f32x4 __attribute__((ext_vector_type(4)));

static const int BB = 16;        // batch
static const int NN = 1024;      // tokens
static const int DD = 768;       // dim

DEV u16 f2bf(float f) {
    unsigned u = __builtin_bit_cast(unsigned, f);
    unsigned r = u + 0x7fffu + ((u >> 16) & 1u);
    return (u16)(r >> 16);
}
DEV float h2f(u16 u) { return (float)__builtin_bit_cast(_Float16, u); }
DEV u16 f2h(float f) { return __builtin_bit_cast(u16, (_Float16)f); }

DEV short8 ld8u(const u16* p) { return *(const short8*)p; }
DEV short8 ldf8_bf(const float* p) {
    float4 f0 = *(const float4*)p;
    float4 f1 = *(const float4*)(p + 4);
    short8 r;
    r[0] = (short)f2bf(f0.x); r[1] = (short)f2bf(f0.y);
    r[2] = (short)f2bf(f0.z); r[3] = (short)f2bf(f0.w);
    r[4] = (short)f2bf(f1.x); r[5] = (short)f2bf(f1.y);
    r[6] = (short)f2bf(f1.z); r[7] = (short)f2bf(f1.w);
    return r;
}

// ---------------------------------------------------------------------------
// NT-GEMM: C[m,n] = scale * sum_k A[m,k] * B[n,k]
// A: [M,K] row-major, B: [N,K] row-major. 64x64 tile, 4 waves (2x2), each wave
// 2x2 mfma_f32_16x16x32_bf16 tiles. Direct-global fragment loads (no LDS).
// Batch z: off = (z%zmod)*s?0 + (z/zmod)*s?1 (element strides).
// OM: 0 = store bf16, 1 = store f16, 2 = store f32.
// ---------------------------------------------------------------------------
template<bool AF32, bool BF32, int OM>
__global__ __launch_bounds__(256) void gemm_nt(
    const void* __restrict__ Ag, const void* __restrict__ Bg, void* __restrict__ Cg,
    int K, int N, int zmod,
    long sA0, long sA1, long sB0, long sB1, long sC0, long sC1,
    float scale)
{
    int z = blockIdx.z;
    long offA = (long)(z % zmod) * sA0 + (long)(z / zmod) * sA1;
    long offB = (long)(z % zmod) * sB0 + (long)(z / zmod) * sB1;
    long offC = (long)(z % zmod) * sC0 + (long)(z / zmod) * sC1;

    const float* Af = (const float*)Ag + offA;
    const u16*   Au = (const u16*)Ag + offA;
    const float* Bf = (const float*)Bg + offB;
    const u16*   Bu = (const u16*)Bg + offB;
    u16*   Cu = (u16*)Cg + offC;
    float* Cf = (float*)Cg + offC;

    int lane = threadIdx.x & 63;
    int wave = threadIdx.x >> 6;
    int wm = wave & 1, wn = wave >> 1;
    int lr = lane & 15, quad = lane >> 4;
    long m0 = (long)blockIdx.x * 64 + wm * 32;
    long n0 = (long)blockIdx.y * 64 + wn * 32;

    f32x4 acc00 = 0, acc01 = 0, acc10 = 0, acc11 = 0;

    for (int k0 = 0; k0 < K; k0 += 32) {
        int kk = k0 + quad * 8;
        short8 a[2], b[2];
#pragma unroll
        for (int t = 0; t < 2; t++) {
            long ar = m0 + t * 16 + lr;
            long br = n0 + t * 16 + lr;
            if constexpr (AF32) a[t] = ldf8_bf(Af + ar * (long)K + kk);
            else                a[t] = ld8u (Au + ar * (long)K + kk);
            if constexpr (BF32) b[t] = ldf8_bf(Bf + br * (long)K + kk);
            else                b[t] = ld8u (Bu + br * (long)K + kk);
        }
        acc00 = __builtin_amdgcn_mfma_f32_16x16x32_bf16(a[0], b[0], acc00, 0, 0, 0);
        acc01 = __builtin_amdgcn_mfma_f32_16x16x32_bf16(a[0], b[1], acc01, 0, 0, 0);
        acc10 = __builtin_amdgcn_mfma_f32_16x16x32_bf16(a[1], b[0], acc10, 0, 0, 0);
        acc11 = __builtin_amdgcn_mfma_f32_16x16x32_bf16(a[1], b[1], acc11, 0, 0, 0);
    }

    f32x4 accs[2][2] = {{acc00, acc01}, {acc10, acc11}};
#pragma unroll
    for (int ti = 0; ti < 2; ti++)
#pragma unroll
        for (int tj = 0; tj < 2; tj++)
#pragma unroll
            for (int r = 0; r < 4; r++) {
                long row = m0 + ti * 16 + quad * 4 + r;
                long col = n0 + tj * 16 + lr;
                float v = accs[ti][tj][r] * scale;
                long idx = row * (long)N + col;
                if constexpr (OM == 0)      Cu[idx] = f2bf(v);
                else if constexpr (OM == 1) Cu[idx] = f2h(v);
                else                        Cf[idx] = v;
            }
}

// ---------------------------------------------------------------------------
// W_s[i,j] = sum_t U[t,i] * S_s[t]^2 * U[t,j]  (symmetric), stored bf16.
// grid (48,48,2), block (16,16). Stores transposed (coalesced; W symmetric).
// ---------------------------------------------------------------------------
__global__ __launch_bounds__(256) void k_compute_w(
    const float* __restrict__ U, const float* __restrict__ S1,
    const float* __restrict__ S2, u16* __restrict__ Wb)
{
    __shared__ float a[16][17], b[16][17];
    int s = blockIdx.z;
    const float* S = s ? S2 : S1;
    int tx = threadIdx.x, ty = threadIdx.y;
    float acc = 0.f;
    for (int t0 = 0; t0 < DD; t0 += 16) {
        int t = t0 + ty;
        float sv = S[t];
        a[ty][tx] = U[(long)t * DD + blockIdx.x * 16 + tx];
        b[ty][tx] = U[(long)t * DD + blockIdx.y * 16 + tx] * (sv * sv);
        __syncthreads();
#pragma unroll
        for (int tt = 0; tt < 16; tt++)
            acc += a[tt][tx] * b[tt][ty];
        __syncthreads();
    }
    // value = W[i=bx*16+tx][j=by*16+ty]; store at [j][i] (symmetric), coalesced
    Wb[(long)s * DD * DD + (long)(blockIdx.y * 16 + ty) * DD + blockIdx.x * 16 + tx] = f2bf(acc);
}

// ---------------------------------------------------------------------------
// y -> yb (bf16, [b][m][d]) and yT (bf16, [b][d][m]) via 32x32 LDS transpose.
// grid (DD/32, NN/32, BB), block (32, 8)
// ---------------------------------------------------------------------------
__global__ __launch_bounds__(256) void k_conv_y(
    const float* __restrict__ y, u16* __restrict__ yb, u16* __restrict__ yT)
{
    __shared__ float tile[32][33];
    int b = blockIdx.z;
    int d0 = blockIdx.x * 32, m0 = blockIdx.y * 32;
    const float* ybase = y + (long)b * NN * DD;
#pragma unroll
    for (int r = 0; r < 32; r += 8) {
        int m = m0 + threadIdx.y + r, d = d0 + threadIdx.x;
        float v = ybase[(long)m * DD + d];
        tile[threadIdx.y + r][threadIdx.x] = v;
        yb[(long)b * NN * DD + (long)m * DD + d] = f2bf(v);
    }
    __syncthreads();
#pragma unroll
    for (int r = 0; r < 32; r += 8) {
        int d = d0 + threadIdx.y + r, m = m0 + threadIdx.x;
        yT[(long)b * DD * NN + (long)d * NN + m] = f2bf(tile[threadIdx.x][threadIdx.y + r]);
    }
}

// ---------------------------------------------------------------------------
// reductions (256 threads = 4 waves)
// ---------------------------------------------------------------------------
DEV float wave_red_max(float v) {
#pragma unroll
    for (int o = 32; o; o >>= 1) v = fmaxf(v, __shfl_xor(v, o));
    return v;
}
DEV float wave_red_sum(float v) {
#pragma unroll
    for (int o = 32; o; o >>= 1) v += __shfl_xor(v, o);
    return v;
}
DEV float block_red_max(float v, float* sh) {
    v = wave_red_max(v);
    if ((threadIdx.x & 63) == 0) sh[threadIdx.x >> 6] = v;
    __syncthreads();
    v = fmaxf(fmaxf(sh[0], sh[1]), fmaxf(sh[2], sh[3]));
    __syncthreads();
    return v;
}
DEV float block_red_sum(float v, float* sh) {
    v = wave_red_sum(v);
    if ((threadIdx.x & 63) == 0) sh[threadIdx.x >> 6] = v;
    __syncthreads();
    v = (sh[0] + sh[1]) + (sh[2] + sh[3]);
    __syncthreads();
    return v;
}

// ---------------------------------------------------------------------------
// P[n,m] = softmax_m( sum_c coords[n,m,c] * pos_emb[n,c] )   (fp32)
// grid (NN), block 256, 4 m per thread
// ---------------------------------------------------------------------------
__global__ __launch_bounds__(256) void k_pos(
    const float* __restrict__ coords, const float* __restrict__ pe,
    float* __restrict__ P)
{
    __shared__ float sh[4];
    int n = blockIdx.x, t = threadIdx.x;
    float p6[6];
#pragma unroll
    for (int c = 0; c < 6; c++) p6[c] = pe[n * 6 + c];
    float v[4];
#pragma unroll
    for (int i = 0; i < 4; i++) {
        const float* cp = coords + ((long)n * NN + t * 4 + i) * 6;
        v[i] = p6[0]*cp[0] + p6[1]*cp[1] + p6[2]*cp[2] + p6[3]*cp[3] + p6[4]*cp[4] + p6[5]*cp[5];
    }
    float mx = block_red_max(fmaxf(fmaxf(v[0], v[1]), fmaxf(v[2], v[3])), sh);
    float e[4], s = 0.f;
#pragma unroll
    for (int i = 0; i < 4; i++) { e[i] = expf(v[i] - mx); s += e[i]; }
    float Z = block_red_sum(s, sh);
    float inv = 1.f / Z;
    float4 o; o.x = e[0]*inv; o.y = e[1]*inv; o.z = e[2]*inv; o.w = e[3]*inv;
    *(float4*)(P + ((long)n << 10) + t * 4) = o;
}

// ---------------------------------------------------------------------------
// Per (b,n) row: softmax both k, blend with pos, entropy, route, write heat
// and selected blended attn row (bf16 bits) IN-PLACE over S plane k=0.
// grid (B*N), block 256, 4 m per thread per k.
// ---------------------------------------------------------------------------
__global__ __launch_bounds__(256) void k_route(
    u16* __restrict__ S, const float* __restrict__ P,
    const float* __restrict__ gating, const float* __restrict__ temp,
    float* __restrict__ heat)
{
    __shared__ float sh[4];
    int bn = blockIdx.x;
    int b = bn >> 10, n = bn & 1023, t = threadIdx.x;
    u16* s1p = S + ((long)(b * 2) << 20) + ((long)n << 10) + t * 4;
    u16* s2p = s1p + (1L << 20);
    const float* pp = P + ((long)n << 10) + t * 4;

    ushort4 r1 = *(const ushort4*)s1p;
    ushort4 r2 = *(const ushort4*)s2p;
    float4 pv = *(const float4*)pp;
    float s1[4] = { h2f(r1.x), h2f(r1.y), h2f(r1.z), h2f(r1.w) };
    float s2[4] = { h2f(r2.x), h2f(r2.y), h2f(r2.z), h2f(r2.w) };
    float p4[4] = { pv.x, pv.y, pv.z, pv.w };

    float mx1 = block_red_max(fmaxf(fmaxf(s1[0], s1[1]), fmaxf(s1[2], s1[3])), sh);
    float mx2 = block_red_max(fmaxf(fmaxf(s2[0], s2[1]), fmaxf(s2[2], s2[3])), sh);

    float e1[4], e2[4], z1 = 0.f, z2 = 0.f;
#pragma unroll
    for (int i = 0; i < 4; i++) {
        e1[i] = expf(s1[i] - mx1); z1 += e1[i];
        e2[i] = expf(s2[i] - mx2); z2 += e2[i];
    }
    float Z1 = block_red_sum(z1, sh);
    float Z2 = block_red_sum(z2, sh);

    float g = 1.f / (1.f + expf(-gating[0]));
    float c1 = (1.f - g) / Z1, c2 = (1.f - g) / Z2;

    float a1[4], a2[4], hh1 = 0.f, hh2 = 0.f;
#pragma unroll
    for (int i = 0; i < 4; i++) {
        a1[i] = e1[i] * c1 + g * p4[i];
        a2[i] = e2[i] * c2 + g * p4[i];
        hh1 -= a1[i] * logf(a1[i] + 1e-8f);
        hh2 -= a2[i] * logf(a2[i] + 1e-8f);
    }
    float H1 = block_red_sum(hh1, sh);
    float H2 = block_red_sum(hh2, sh);

    float tv = temp[0];
    float hm0 = 2.f - 2.f / (1.f + expf(-tv * H1));
    float hm1 = 2.f - 2.f / (1.f + expf(-tv * H2));
    int ks = (hm0 >= hm1) ? 0 : 1;
    if (t == 0) heat[bn] = ks ? hm1 : hm0;

    ushort4 w;
    w.x = f2bf(ks ? a2[0] : a1[0]);
    w.y = f2bf(ks ? a2[1] : a1[1]);
    w.z = f2bf(ks ? a2[2] : a1[2]);
    w.w = f2bf(ks ? a2[3] : a1[3]);
    *(ushort4*)s1p = w;   // attn_c (bf16 bits) over k=0 score plane
}

// ---------------------------------------------------------------------------
extern "C" void kernel_launch(void* const* d_in, const int* in_sizes, int n_in,
                              void* d_out, int out_size, void* d_ws, size_t ws_size,
                              hipStream_t stream)
{
    (void)in_sizes; (void)n_in; (void)out_size; (void)ws_size;
    const float* x      = (const float*)d_in[0];
    const float* y      = (const float*)d_in[1];
    const float* coords = (const float*)d_in[2];
    const float* U      = (const float*)d_in[3];
    const float* S1     = (const float*)d_in[4];
    const float* S2     = (const float*)d_in[5];
    const float* gating = (const float*)d_in[6];
    const float* temp   = (const float*)d_in[7];
    const float* pose   = (const float*)d_in[8];

    float* out  = (float*)d_out;
    float* heat = out + (long)BB * NN * DD;

    char* w = (char*)d_ws;
    u16* Wb  = (u16*)w;  w += (long)2 * DD * DD * 2;        //  2.25 MB
    u16* x12 = (u16*)w;  w += (long)2 * BB * NN * DD * 2;   // 48 MB
    u16* yb  = (u16*)w;  w += (long)BB * NN * DD * 2;       // 24 MB
    u16* yT  = (u16*)w;  w += (long)BB * DD * NN * 2;       // 24 MB
    u16* S   = (u16*)w;  w += (long)BB * 2 * NN * NN * 2;   // 64 MB
    float* P = (float*)w;                                   //  4 MB

    const long MBN = (long)BB * NN * DD;       // 12,582,912 (x1/x2 plane)
    const long BND = (long)NN * DD;            //    786,432 (per-b x/y plane)
    const long SPL = (long)NN * NN;            //  1,048,576 (score plane)

    k_compute_w<<<dim3(48, 48, 2), dim3(16, 16), 0, stream>>>(U, S1, S2, Wb);
    k_conv_y<<<dim3(DD / 32, NN / 32, BB), dim3(32, 8), 0, stream>>>(y, yb, yT);
    k_pos<<<dim3(NN), dim3(256), 0, stream>>>(coords, pose, P);

    // x12[s] = x @ W_s   (A f32 -> bf16 on load, B bf16, C bf16)
    gemm_nt<true, false, 0><<<dim3(BB * NN / 64, DD / 64, 2), dim3(256), 0, stream>>>(
        x, Wb, x12, DD, DD, 2,
        0L, 0L, (long)DD * DD, 0L, MBN, 0L, 1.0f);

    // S[b,k] = scale * x_k[b] @ y[b]^T   (C f16); z = b*2 + k
    gemm_nt<false, false, 1><<<dim3(NN / 64, NN / 64, BB * 2), dim3(256), 0, stream>>>(
        x12, yb, S, DD, NN, 2,
        MBN, BND, 0L, BND, SPL, 2 * SPL, 0.036084391824351615f);

    // softmax + blend + entropy + route; attn_c (bf16) in-place at k=0 plane
    k_route<<<dim3(BB * NN), dim3(256), 0, stream>>>(S, P, gating, temp, heat);

    // out[b] = attn_c[b] @ y[b]   (A bf16 in S k=0 plane, B = yT bf16, C f32)
    gemm_nt<false, false, 2><<<dim3(NN / 64, DD / 64, BB), dim3(256), 0, stream>>>(
        S, yT, out, NN, DD, 1,
        0L, 2 * SPL, 0L, BND, 0L, BND, 1.0f);
}

// Round 2
// 516.540 us; speedup vs baseline: 2.3680x; 2.3680x over previous
//
#include <hip/hip_runtime.h>
#include <hip/hip_bf16.h>

#define DEV __device__ __forceinline__

typedef unsigned short u16;
typedef short short8 __attribute__((ext_vector_type(8)));
typedef float f32x4 __attribute__((ext_vector_type(4)));

static const int BB = 16;        // batch
static const int NN = 1024;      // tokens
static const int DD = 768;       // dim

DEV u16 f2bf(float f) {
    unsigned u = __builtin_bit_cast(unsigned, f);
    unsigned r = u + 0x7fffu + ((u >> 16) & 1u);
    return (u16)(r >> 16);
}
DEV float h2f(u16 u) { return (float)__builtin_bit_cast(_Float16, u); }
DEV u16 f2h(float f) { return __builtin_bit_cast(u16, (_Float16)f); }

DEV short8 ldf8_bf(const float* p) {
    float4 f0 = *(const float4*)p;
    float4 f1 = *(const float4*)(p + 4);
    short8 r;
    r[0] = (short)f2bf(f0.x); r[1] = (short)f2bf(f0.y);
    r[2] = (short)f2bf(f0.z); r[3] = (short)f2bf(f0.w);
    r[4] = (short)f2bf(f1.x); r[5] = (short)f2bf(f1.y);
    r[6] = (short)f2bf(f1.z); r[7] = (short)f2bf(f1.w);
    return r;
}

// async 16B global->LDS (direct-to-shared DMA); LDS dest = wave-uniform base + lane*16
DEV void gl_lds16(const u16* g, u16* l) {
    __builtin_amdgcn_global_load_lds(
        (const __attribute__((address_space(1))) unsigned int*)g,
        (__attribute__((address_space(3))) unsigned int*)l, 16, 0, 0);
}

// ---------------------------------------------------------------------------
// m97-style NT-GEMM: C[m,n] = scale * sum_k A[m,k]*B[n,k], A/B bf16 row-major.
// 128x128 tile, BK=32, 4 waves (2x2), each wave 4x4 mfma_f32_16x16x32_bf16.
// LDS: As/Bs 128x32 bf16 (8KB each), 16B-chunk XOR swizzle q' = q ^ ((row>>1)&3)
//   -> staging fully coalesced (64B/row), fragment ds_read_b128 2-way banks (free).
// Batch z: off = (z%zmod)*s?0 + (z/zmod)*s?1 (element strides).
// OM: 0 = store bf16, 1 = store f16, 2 = store f32.
// ---------------------------------------------------------------------------
template<int OM>
__global__ __launch_bounds__(256) void gemm128(
    const u16* __restrict__ Ag, const u16* __restrict__ Bg, void* __restrict__ Cg,
    int K, int N, int zmod,
    long sA0, long sA1, long sB0, long sB1, long sC0, long sC1,
    float scale)
{
    __shared__ u16 As[128 * 32];
    __shared__ u16 Bs[128 * 32];

    int z = blockIdx.z;
    const u16* A = Ag + (long)(z % zmod) * sA0 + (long)(z / zmod) * sA1;
    const u16* B = Bg + (long)(z % zmod) * sB0 + (long)(z / zmod) * sB1;
    u16*   Cu = (u16*)Cg   + (long)(z % zmod) * sC0 + (long)(z / zmod) * sC1;
    float* Cf = (float*)Cg + (long)(z % zmod) * sC0 + (long)(z / zmod) * sC1;

    int tid  = threadIdx.x;
    int lane = tid & 63, wave = tid >> 6;
    int wm = wave & 1, wn = wave >> 1;
    int lr = lane & 15, quad = lane >> 4;

    long m0 = (long)blockIdx.x * 128;
    long n0 = (long)blockIdx.y * 128;

    // staging: chunk p in [0,512): LDS pos p -> (row = p>>2, qs = p&3) holds
    // global chunk q = qs ^ ((row>>1)&3). p = i*256 + tid keeps lane*16 contiguity.
    int p0 = tid, p1 = tid + 256;
    int ar0 = p0 >> 2, aq0 = (p0 & 3) ^ ((ar0 >> 1) & 3);
    int ar1 = p1 >> 2, aq1 = (p1 & 3) ^ ((ar1 >> 1) & 3);
    const u16* a0p = A + (m0 + ar0) * (long)K + aq0 * 8;
    const u16* a1p = A + (m0 + ar1) * (long)K + aq1 * 8;
    const u16* b0p = B + (n0 + ar0) * (long)K + aq0 * 8;
    const u16* b1p = B + (n0 + ar1) * (long)K + aq1 * 8;
    u16* lA0 = As + p0 * 8;  u16* lA1 = As + p1 * 8;
    u16* lB0 = Bs + p0 * 8;  u16* lB1 = Bs + p1 * 8;

    // fragment LDS offsets (u16 elements): row*32 + (quad ^ ((row>>1)&3))*8
    int aoff[4], boff[4];
#pragma unroll
    for (int t = 0; t < 4; t++) {
        int ra = wm * 64 + t * 16 + lr;
        int rb = wn * 64 + t * 16 + lr;
        aoff[t] = ra * 32 + ((quad ^ ((ra >> 1) & 3)) * 8);
        boff[t] = rb * 32 + ((quad ^ ((rb >> 1) & 3)) * 8);
    }

    f32x4 acc[4][4] = {};

    for (int k0 = 0; k0 < K; k0 += 32) {
        gl_lds16(a0p + k0, lA0);
        gl_lds16(a1p + k0, lA1);
        gl_lds16(b0p + k0, lB0);
        gl_lds16(b1p + k0, lB1);
        __syncthreads();   // vmcnt(0) drain + barrier: staging visible

        short8 af[4], bfr[4];
#pragma unroll
        for (int t = 0; t < 4; t++) af[t]  = *(const short8*)(As + aoff[t]);
#pragma unroll
        for (int t = 0; t < 4; t++) bfr[t] = *(const short8*)(Bs + boff[t]);
#pragma unroll
        for (int ti = 0; ti < 4; ti++)
#pragma unroll
            for (int tj = 0; tj < 4; tj++)
                acc[ti][tj] = __builtin_amdgcn_mfma_f32_16x16x32_bf16(
                    af[ti], bfr[tj], acc[ti][tj], 0, 0, 0);
        __syncthreads();   // protect LDS from next staging round
    }

    long crow = m0 + wm * 64 + quad * 4;
    long ccol = n0 + wn * 64 + lr;
#pragma unroll
    for (int ti = 0; ti < 4; ti++)
#pragma unroll
        for (int tj = 0; tj < 4; tj++)
#pragma unroll
            for (int r = 0; r < 4; r++) {
                long row = crow + ti * 16 + r;
                long col = ccol + tj * 16;
                float v = acc[ti][tj][r] * scale;
                long idx = row * (long)N + col;
                if constexpr (OM == 0)      Cu[idx] = f2bf(v);
                else if constexpr (OM == 1) Cu[idx] = f2h(v);
                else                        Cf[idx] = v;
            }
}

// ---------------------------------------------------------------------------
// W_s[i,j] = sum_t U[t,i] * S_s[t]^2 * U[t,j]  (symmetric), stored bf16.
// grid (48,48,2), block (16,16). Stores transposed (coalesced; W symmetric).
// ---------------------------------------------------------------------------
__global__ __launch_bounds__(256) void k_compute_w(
    const float* __restrict__ U, const float* __restrict__ S1,
    const float* __restrict__ S2, u16* __restrict__ Wb)
{
    __shared__ float a[16][17], b[16][17];
    int s = blockIdx.z;
    const float* S = s ? S2 : S1;
    int tx = threadIdx.x, ty = threadIdx.y;
    float acc = 0.f;
    for (int t0 = 0; t0 < DD; t0 += 16) {
        int t = t0 + ty;
        float sv = S[t];
        a[ty][tx] = U[(long)t * DD + blockIdx.x * 16 + tx];
        b[ty][tx] = U[(long)t * DD + blockIdx.y * 16 + tx] * (sv * sv);
        __syncthreads();
#pragma unroll
        for (int tt = 0; tt < 16; tt++)
            acc += a[tt][tx] * b[tt][ty];
        __syncthreads();
    }
    Wb[(long)s * DD * DD + (long)(blockIdx.y * 16 + ty) * DD + blockIdx.x * 16 + tx] = f2bf(acc);
}

// ---------------------------------------------------------------------------
// x (f32) -> xb (bf16), flat. grid (MBN/2048), block 256, 8 elems/thread.
// ---------------------------------------------------------------------------
__global__ __launch_bounds__(256) void k_conv_x(
    const float* __restrict__ x, u16* __restrict__ xb)
{
    long i = ((long)blockIdx.x * 256 + threadIdx.x) * 8;
    *(short8*)(xb + i) = ldf8_bf(x + i);
}

// ---------------------------------------------------------------------------
// y -> yb (bf16, [b][m][d]) and yT (bf16, [b][d][m]) via 32x32 LDS transpose.
// grid (DD/32, NN/32, BB), block (32, 8)
// ---------------------------------------------------------------------------
__global__ __launch_bounds__(256) void k_conv_y(
    const float* __restrict__ y, u16* __restrict__ yb, u16* __restrict__ yT)
{
    __shared__ float tile[32][33];
    int b = blockIdx.z;
    int d0 = blockIdx.x * 32, m0 = blockIdx.y * 32;
    const float* ybase = y + (long)b * NN * DD;
#pragma unroll
    for (int r = 0; r < 32; r += 8) {
        int m = m0 + threadIdx.y + r, d = d0 + threadIdx.x;
        float v = ybase[(long)m * DD + d];
        tile[threadIdx.y + r][threadIdx.x] = v;
        yb[(long)b * NN * DD + (long)m * DD + d] = f2bf(v);
    }
    __syncthreads();
#pragma unroll
    for (int r = 0; r < 32; r += 8) {
        int d = d0 + threadIdx.y + r, m = m0 + threadIdx.x;
        yT[(long)b * DD * NN + (long)d * NN + m] = f2bf(tile[threadIdx.x][threadIdx.y + r]);
    }
}

// ---------------------------------------------------------------------------
// reductions (256 threads = 4 waves)
// ---------------------------------------------------------------------------
DEV float wave_red_max(float v) {
#pragma unroll
    for (int o = 32; o; o >>= 1) v = fmaxf(v, __shfl_xor(v, o));
    return v;
}
DEV float wave_red_sum(float v) {
#pragma unroll
    for (int o = 32; o; o >>= 1) v += __shfl_xor(v, o);
    return v;
}
DEV float block_red_max(float v, float* sh) {
    v = wave_red_max(v);
    if ((threadIdx.x & 63) == 0) sh[threadIdx.x >> 6] = v;
    __syncthreads();
    v = fmaxf(fmaxf(sh[0], sh[1]), fmaxf(sh[2], sh[3]));
    __syncthreads();
    return v;
}
DEV float block_red_sum(float v, float* sh) {
    v = wave_red_sum(v);
    if ((threadIdx.x & 63) == 0) sh[threadIdx.x >> 6] = v;
    __syncthreads();
    v = (sh[0] + sh[1]) + (sh[2] + sh[3]);
    __syncthreads();
    return v;
}

// ---------------------------------------------------------------------------
// P[n,m] = softmax_m( sum_c coords[n,m,c] * pos_emb[n,c] )   (fp32)
// grid (NN), block 256, 4 m per thread
// ---------------------------------------------------------------------------
__global__ __launch_bounds__(256) void k_pos(
    const float* __restrict__ coords, const float* __restrict__ pe,
    float* __restrict__ P)
{
    __shared__ float sh[4];
    int n = blockIdx.x, t = threadIdx.x;
    float p6[6];
#pragma unroll
    for (int c = 0; c < 6; c++) p6[c] = pe[n * 6 + c];
    float v[4];
#pragma unroll
    for (int i = 0; i < 4; i++) {
        const float* cp = coords + ((long)n * NN + t * 4 + i) * 6;
        v[i] = p6[0]*cp[0] + p6[1]*cp[1] + p6[2]*cp[2] + p6[3]*cp[3] + p6[4]*cp[4] + p6[5]*cp[5];
    }
    float mx = block_red_max(fmaxf(fmaxf(v[0], v[1]), fmaxf(v[2], v[3])), sh);
    float e[4], s = 0.f;
#pragma unroll
    for (int i = 0; i < 4; i++) { e[i] = expf(v[i] - mx); s += e[i]; }
    float Z = block_red_sum(s, sh);
    float inv = 1.f / Z;
    float4 o; o.x = e[0]*inv; o.y = e[1]*inv; o.z = e[2]*inv; o.w = e[3]*inv;
    *(float4*)(P + ((long)n << 10) + t * 4) = o;
}

// ---------------------------------------------------------------------------
// Per (b,n) row: softmax both k, blend with pos, entropy, route, write heat
// and selected blended attn row (bf16 bits) IN-PLACE over S plane k=0.
// grid (B*N), block 256, 4 m per thread per k.
// ---------------------------------------------------------------------------
__global__ __launch_bounds__(256) void k_route(
    u16* __restrict__ S, const float* __restrict__ P,
    const float* __restrict__ gating, const float* __restrict__ temp,
    float* __restrict__ heat)
{
    __shared__ float sh[4];
    int bn = blockIdx.x;
    int b = bn >> 10, n = bn & 1023, t = threadIdx.x;
    u16* s1p = S + ((long)(b * 2) << 20) + ((long)n << 10) + t * 4;
    u16* s2p = s1p + (1L << 20);
    const float* pp = P + ((long)n << 10) + t * 4;

    ushort4 r1 = *(const ushort4*)s1p;
    ushort4 r2 = *(const ushort4*)s2p;
    float4 pv = *(const float4*)pp;
    float s1[4] = { h2f(r1.x), h2f(r1.y), h2f(r1.z), h2f(r1.w) };
    float s2[4] = { h2f(r2.x), h2f(r2.y), h2f(r2.z), h2f(r2.w) };
    float p4[4] = { pv.x, pv.y, pv.z, pv.w };

    float mx1 = block_red_max(fmaxf(fmaxf(s1[0], s1[1]), fmaxf(s1[2], s1[3])), sh);
    float mx2 = block_red_max(fmaxf(fmaxf(s2[0], s2[1]), fmaxf(s2[2], s2[3])), sh);

    float e1[4], e2[4], z1 = 0.f, z2 = 0.f;
#pragma unroll
    for (int i = 0; i < 4; i++) {
        e1[i] = expf(s1[i] - mx1); z1 += e1[i];
        e2[i] = expf(s2[i] - mx2); z2 += e2[i];
    }
    float Z1 = block_red_sum(z1, sh);
    float Z2 = block_red_sum(z2, sh);

    float g = 1.f / (1.f + expf(-gating[0]));
    float c1 = (1.f - g) / Z1, c2 = (1.f - g) / Z2;

    float a1[4], a2[4], hh1 = 0.f, hh2 = 0.f;
#pragma unroll
    for (int i = 0; i < 4; i++) {
        a1[i] = e1[i] * c1 + g * p4[i];
        a2[i] = e2[i] * c2 + g * p4[i];
        hh1 -= a1[i] * logf(a1[i] + 1e-8f);
        hh2 -= a2[i] * logf(a2[i] + 1e-8f);
    }
    float H1 = block_red_sum(hh1, sh);
    float H2 = block_red_sum(hh2, sh);

    float tv = temp[0];
    float hm0 = 2.f - 2.f / (1.f + expf(-tv * H1));
    float hm1 = 2.f - 2.f / (1.f + expf(-tv * H2));
    int ks = (hm0 >= hm1) ? 0 : 1;
    if (t == 0) heat[bn] = ks ? hm1 : hm0;

    ushort4 w;
    w.x = f2bf(ks ? a2[0] : a1[0]);
    w.y = f2bf(ks ? a2[1] : a1[1]);
    w.z = f2bf(ks ? a2[2] : a1[2]);
    w.w = f2bf(ks ? a2[3] : a1[3]);
    *(ushort4*)s1p = w;   // attn_c (bf16 bits) over k=0 score plane
}

// ---------------------------------------------------------------------------
extern "C" void kernel_launch(void* const* d_in, const int* in_sizes, int n_in,
                              void* d_out, int out_size, void* d_ws, size_t ws_size,
                              hipStream_t stream)
{
    (void)in_sizes; (void)n_in; (void)out_size; (void)ws_size;
    const float* x      = (const float*)d_in[0];
    const float* y      = (const float*)d_in[1];
    const float* coords = (const float*)d_in[2];
    const float* U      = (const float*)d_in[3];
    const float* S1     = (const float*)d_in[4];
    const float* S2     = (const float*)d_in[5];
    const float* gating = (const float*)d_in[6];
    const float* temp   = (const float*)d_in[7];
    const float* pose   = (const float*)d_in[8];

    float* out  = (float*)d_out;
    float* heat = out + (long)BB * NN * DD;

    char* w = (char*)d_ws;
    u16* Wb  = (u16*)w;  w += (long)2 * DD * DD * 2;        //  2.25 MB
    u16* xb  = (u16*)w;  w += (long)BB * NN * DD * 2;       // 24 MB
    u16* x12 = (u16*)w;  w += (long)2 * BB * NN * DD * 2;   // 48 MB
    u16* yb  = (u16*)w;  w += (long)BB * NN * DD * 2;       // 24 MB
    u16* yT  = (u16*)w;  w += (long)BB * DD * NN * 2;       // 24 MB
    u16* S   = (u16*)w;  w += (long)BB * 2 * NN * NN * 2;   // 64 MB
    float* P = (float*)w;                                   //  4 MB

    const long MBN = (long)BB * NN * DD;       // x1/x2 plane elements
    const long BND = (long)NN * DD;            // per-b x/y plane
    const long SPL = (long)NN * NN;            // score plane

    k_compute_w<<<dim3(48, 48, 2), dim3(16, 16), 0, stream>>>(U, S1, S2, Wb);
    k_conv_x<<<dim3(MBN / 2048), dim3(256), 0, stream>>>(x, xb);
    k_conv_y<<<dim3(DD / 32, NN / 32, BB), dim3(32, 8), 0, stream>>>(y, yb, yT);
    k_pos<<<dim3(NN), dim3(256), 0, stream>>>(coords, pose, P);

    // x12[s] = xb @ W_s^T-as-NT   (C bf16); z = s
    gemm128<0><<<dim3(BB * NN / 128, DD / 128, 2), dim3(256), 0, stream>>>(
        xb, Wb, x12, DD, DD, 2,
        0L, 0L, (long)DD * DD, 0L, MBN, 0L, 1.0f);

    // S[b,k] = scale * x_k[b] @ y[b]^T   (C f16); z = b*2 + k
    gemm128<1><<<dim3(NN / 128, NN / 128, BB * 2), dim3(256), 0, stream>>>(
        x12, yb, S, DD, NN, 2,
        MBN, BND, 0L, BND, SPL, 2 * SPL, 0.036084391824351615f);

    // softmax + blend + entropy + route; attn_c (bf16) in-place at k=0 plane
    k_route<<<dim3(BB * NN), dim3(256), 0, stream>>>(S, P, gating, temp, heat);

    // out[b] = attn_c[b] @ y[b]   (A bf16 in S k=0 plane, B = yT bf16, C f32)
    gemm128<2><<<dim3(NN / 128, DD / 128, BB), dim3(256), 0, stream>>>(
        S, yT, out, NN, DD, 1,
        0L, 2 * SPL, 0L, BND, 0L, BND, 1.0f);
}

// Round 3
// 431.316 us; speedup vs baseline: 2.8359x; 1.1976x over previous
//
#include <hip/hip_runtime.h>
#include <hip/hip_bf16.h>

#define DEV __device__ __forceinline__

typedef unsigned short u16;
typedef short short8 __attribute__((ext_vector_type(8)));
typedef float f32x4 __attribute__((ext_vector_type(4)));

static const int BB = 16;        // batch
static const int NN = 1024;      // tokens
static const int DD = 768;       // dim

DEV u16 f2bf(float f) {
    unsigned u = __builtin_bit_cast(unsigned, f);
    unsigned r = u + 0x7fffu + ((u >> 16) & 1u);
    return (u16)(r >> 16);
}
DEV float h2f(u16 u) { return (float)__builtin_bit_cast(_Float16, u); }
DEV u16 f2h(float f) { return __builtin_bit_cast(u16, (_Float16)f); }

DEV short8 ldf8_bf(const float* p) {
    float4 f0 = *(const float4*)p;
    float4 f1 = *(const float4*)(p + 4);
    short8 r;
    r[0] = (short)f2bf(f0.x); r[1] = (short)f2bf(f0.y);
    r[2] = (short)f2bf(f0.z); r[3] = (short)f2bf(f0.w);
    r[4] = (short)f2bf(f1.x); r[5] = (short)f2bf(f1.y);
    r[6] = (short)f2bf(f1.z); r[7] = (short)f2bf(f1.w);
    return r;
}

// async 16B global->LDS (direct-to-shared DMA); LDS dest = wave-uniform base + lane*16
DEV void gl_lds16(const u16* g, u16* l) {
    __builtin_amdgcn_global_load_lds(
        (const __attribute__((address_space(1))) unsigned int*)g,
        (__attribute__((address_space(3))) unsigned int*)l, 16, 0, 0);
}

// ---------------------------------------------------------------------------
// m97-style NT-GEMM: C[m,n] = scale * sum_k A[m,k]*B[n,k], A/B bf16 row-major.
// 128x128 tile, BK=32, 4 waves (2x2), each wave 4x4 mfma_f32_16x16x32_bf16.
// LDS: As/Bs 128x32 bf16 (8KB each), 16B-chunk XOR swizzle q' = q ^ ((row>>1)&3)
//   -> staging fully coalesced (64B/row), fragment ds_read_b128 2-way banks (free).
// Batch z: off = (z%zmod)*s?0 + (z/zmod)*s?1 (element strides).
// OM: 0 = store bf16, 1 = store f16, 2 = store f32.
// ---------------------------------------------------------------------------
template<int OM>
__global__ __launch_bounds__(256) void gemm128(
    const u16* __restrict__ Ag, const u16* __restrict__ Bg, void* __restrict__ Cg,
    int K, int N, int zmod,
    long sA0, long sA1, long sB0, long sB1, long sC0, long sC1,
    float scale)
{
    __shared__ u16 As[128 * 32];
    __shared__ u16 Bs[128 * 32];

    int z = blockIdx.z;
    const u16* A = Ag + (long)(z % zmod) * sA0 + (long)(z / zmod) * sA1;
    const u16* B = Bg + (long)(z % zmod) * sB0 + (long)(z / zmod) * sB1;
    u16*   Cu = (u16*)Cg   + (long)(z % zmod) * sC0 + (long)(z / zmod) * sC1;
    float* Cf = (float*)Cg + (long)(z % zmod) * sC0 + (long)(z / zmod) * sC1;

    int tid  = threadIdx.x;
    int lane = tid & 63, wave = tid >> 6;
    int wm = wave & 1, wn = wave >> 1;
    int lr = lane & 15, quad = lane >> 4;

    long m0 = (long)blockIdx.x * 128;
    long n0 = (long)blockIdx.y * 128;

    // staging: chunk p in [0,512): LDS pos p -> (row = p>>2, qs = p&3) holds
    // global chunk q = qs ^ ((row>>1)&3). p = i*256 + tid keeps lane*16 contiguity.
    int p0 = tid, p1 = tid + 256;
    int ar0 = p0 >> 2, aq0 = (p0 & 3) ^ ((ar0 >> 1) & 3);
    int ar1 = p1 >> 2, aq1 = (p1 & 3) ^ ((ar1 >> 1) & 3);
    const u16* a0p = A + (m0 + ar0) * (long)K + aq0 * 8;
    const u16* a1p = A + (m0 + ar1) * (long)K + aq1 * 8;
    const u16* b0p = B + (n0 + ar0) * (long)K + aq0 * 8;
    const u16* b1p = B + (n0 + ar1) * (long)K + aq1 * 8;
    u16* lA0 = As + p0 * 8;  u16* lA1 = As + p1 * 8;
    u16* lB0 = Bs + p0 * 8;  u16* lB1 = Bs + p1 * 8;

    // fragment LDS offsets (u16 elements): row*32 + (quad ^ ((row>>1)&3))*8
    int aoff[4], boff[4];
#pragma unroll
    for (int t = 0; t < 4; t++) {
        int ra = wm * 64 + t * 16 + lr;
        int rb = wn * 64 + t * 16 + lr;
        aoff[t] = ra * 32 + ((quad ^ ((ra >> 1) & 3)) * 8);
        boff[t] = rb * 32 + ((quad ^ ((rb >> 1) & 3)) * 8);
    }

    f32x4 acc[4][4] = {};

    for (int k0 = 0; k0 < K; k0 += 32) {
        gl_lds16(a0p + k0, lA0);
        gl_lds16(a1p + k0, lA1);
        gl_lds16(b0p + k0, lB0);
        gl_lds16(b1p + k0, lB1);
        __syncthreads();   // vmcnt(0) drain + barrier: staging visible

        short8 af[4], bfr[4];
#pragma unroll
        for (int t = 0; t < 4; t++) af[t]  = *(const short8*)(As + aoff[t]);
#pragma unroll
        for (int t = 0; t < 4; t++) bfr[t] = *(const short8*)(Bs + boff[t]);
#pragma unroll
        for (int ti = 0; ti < 4; ti++)
#pragma unroll
            for (int tj = 0; tj < 4; tj++)
                acc[ti][tj] = __builtin_amdgcn_mfma_f32_16x16x32_bf16(
                    af[ti], bfr[tj], acc[ti][tj], 0, 0, 0);
        __syncthreads();   // protect LDS from next staging round
    }

    long crow = m0 + wm * 64 + quad * 4;
    long ccol = n0 + wn * 64 + lr;
#pragma unroll
    for (int ti = 0; ti < 4; ti++)
#pragma unroll
        for (int tj = 0; tj < 4; tj++)
#pragma unroll
            for (int r = 0; r < 4; r++) {
                long row = crow + ti * 16 + r;
                long col = ccol + tj * 16;
                float v = acc[ti][tj][r] * scale;
                long idx = row * (long)N + col;
                if constexpr (OM == 0)      Cu[idx] = f2bf(v);
                else if constexpr (OM == 1) Cu[idx] = f2h(v);
                else                        Cf[idx] = v;
            }
}

// ---------------------------------------------------------------------------
// Prep: Ub = bf16(U) (row-major), VT_s[j,i] = bf16(S_s[i]^2 * U[i,j]).
// 32x32 LDS transpose tiles. grid (24,24), block (32,8).
// ---------------------------------------------------------------------------
__global__ __launch_bounds__(256) void k_prep_u(
    const float* __restrict__ U, const float* __restrict__ S1,
    const float* __restrict__ S2, u16* __restrict__ Ub,
    u16* __restrict__ VT1, u16* __restrict__ VT2)
{
    __shared__ float tile[32][33];
    int i0 = blockIdx.x * 32, j0 = blockIdx.y * 32;
#pragma unroll
    for (int r = 0; r < 32; r += 8) {
        int i = i0 + threadIdx.y + r, j = j0 + threadIdx.x;
        float v = U[(long)i * DD + j];
        tile[threadIdx.y + r][threadIdx.x] = v;
        Ub[(long)i * DD + j] = f2bf(v);
    }
    __syncthreads();
    float s1v = S1[i0 + threadIdx.x];
    float s2v = S2[i0 + threadIdx.x];
    s1v *= s1v; s2v *= s2v;
#pragma unroll
    for (int r = 0; r < 32; r += 8) {
        int j = j0 + threadIdx.y + r, i = i0 + threadIdx.x;
        float v = tile[threadIdx.x][threadIdx.y + r];   // U[i][j]
        VT1[(long)j * DD + i] = f2bf(s1v * v);
        VT2[(long)j * DD + i] = f2bf(s2v * v);
    }
}

// ---------------------------------------------------------------------------
// x (f32) -> xb (bf16), flat. grid (MBN/2048), block 256, 8 elems/thread.
// ---------------------------------------------------------------------------
__global__ __launch_bounds__(256) void k_conv_x(
    const float* __restrict__ x, u16* __restrict__ xb)
{
    long i = ((long)blockIdx.x * 256 + threadIdx.x) * 8;
    *(short8*)(xb + i) = ldf8_bf(x + i);
}

// ---------------------------------------------------------------------------
// y -> yb (bf16, [b][m][d]) and yT (bf16, [b][d][m]) via 32x32 LDS transpose.
// grid (DD/32, NN/32, BB), block (32, 8)
// ---------------------------------------------------------------------------
__global__ __launch_bounds__(256) void k_conv_y(
    const float* __restrict__ y, u16* __restrict__ yb, u16* __restrict__ yT)
{
    __shared__ float tile[32][33];
    int b = blockIdx.z;
    int d0 = blockIdx.x * 32, m0 = blockIdx.y * 32;
    const float* ybase = y + (long)b * NN * DD;
#pragma unroll
    for (int r = 0; r < 32; r += 8) {
        int m = m0 + threadIdx.y + r, d = d0 + threadIdx.x;
        float v = ybase[(long)m * DD + d];
        tile[threadIdx.y + r][threadIdx.x] = v;
        yb[(long)b * NN * DD + (long)m * DD + d] = f2bf(v);
    }
    __syncthreads();
#pragma unroll
    for (int r = 0; r < 32; r += 8) {
        int d = d0 + threadIdx.y + r, m = m0 + threadIdx.x;
        yT[(long)b * DD * NN + (long)d * NN + m] = f2bf(tile[threadIdx.x][threadIdx.y + r]);
    }
}

// ---------------------------------------------------------------------------
// reductions (256 threads = 4 waves)
// ---------------------------------------------------------------------------
DEV float wave_red_max(float v) {
#pragma unroll
    for (int o = 32; o; o >>= 1) v = fmaxf(v, __shfl_xor(v, o));
    return v;
}
DEV float wave_red_sum(float v) {
#pragma unroll
    for (int o = 32; o; o >>= 1) v += __shfl_xor(v, o);
    return v;
}
DEV float block_red_max(float v, float* sh) {
    v = wave_red_max(v);
    if ((threadIdx.x & 63) == 0) sh[threadIdx.x >> 6] = v;
    __syncthreads();
    v = fmaxf(fmaxf(sh[0], sh[1]), fmaxf(sh[2], sh[3]));
    __syncthreads();
    return v;
}
DEV float block_red_sum(float v, float* sh) {
    v = wave_red_sum(v);
    if ((threadIdx.x & 63) == 0) sh[threadIdx.x >> 6] = v;
    __syncthreads();
    v = (sh[0] + sh[1]) + (sh[2] + sh[3]);
    __syncthreads();
    return v;
}

// ---------------------------------------------------------------------------
// P[n,m] = softmax_m( sum_c coords[n,m,c] * pos_emb[n,c] )   (fp32)
// grid (NN), block 256, 4 m per thread
// ---------------------------------------------------------------------------
__global__ __launch_bounds__(256) void k_pos(
    const float* __restrict__ coords, const float* __restrict__ pe,
    float* __restrict__ P)
{
    __shared__ float sh[4];
    int n = blockIdx.x, t = threadIdx.x;
    float p6[6];
#pragma unroll
    for (int c = 0; c < 6; c++) p6[c] = pe[n * 6 + c];
    float v[4];
#pragma unroll
    for (int i = 0; i < 4; i++) {
        const float* cp = coords + ((long)n * NN + t * 4 + i) * 6;
        v[i] = p6[0]*cp[0] + p6[1]*cp[1] + p6[2]*cp[2] + p6[3]*cp[3] + p6[4]*cp[4] + p6[5]*cp[5];
    }
    float mx = block_red_max(fmaxf(fmaxf(v[0], v[1]), fmaxf(v[2], v[3])), sh);
    float e[4], s = 0.f;
#pragma unroll
    for (int i = 0; i < 4; i++) { e[i] = expf(v[i] - mx); s += e[i]; }
    float Z = block_red_sum(s, sh);
    float inv = 1.f / Z;
    float4 o; o.x = e[0]*inv; o.y = e[1]*inv; o.z = e[2]*inv; o.w = e[3]*inv;
    *(float4*)(P + ((long)n << 10) + t * 4) = o;
}

// ---------------------------------------------------------------------------
// Per (b,n) row: softmax both k, blend with pos, entropy, route, write heat
// and selected blended attn row (bf16 bits) IN-PLACE over S plane k=0.
// grid (B*N), block 256, 4 m per thread per k.
// ---------------------------------------------------------------------------
__global__ __launch_bounds__(256) void k_route(
    u16* __restrict__ S, const float* __restrict__ P,
    const float* __restrict__ gating, const float* __restrict__ temp,
    float* __restrict__ heat)
{
    __shared__ float sh[4];
    int bn = blockIdx.x;
    int b = bn >> 10, n = bn & 1023, t = threadIdx.x;
    u16* s1p = S + ((long)(b * 2) << 20) + ((long)n << 10) + t * 4;
    u16* s2p = s1p + (1L << 20);
    const float* pp = P + ((long)n << 10) + t * 4;

    ushort4 r1 = *(const ushort4*)s1p;
    ushort4 r2 = *(const ushort4*)s2p;
    float4 pv = *(const float4*)pp;
    float s1[4] = { h2f(r1.x), h2f(r1.y), h2f(r1.z), h2f(r1.w) };
    float s2[4] = { h2f(r2.x), h2f(r2.y), h2f(r2.z), h2f(r2.w) };
    float p4[4] = { pv.x, pv.y, pv.z, pv.w };

    float mx1 = block_red_max(fmaxf(fmaxf(s1[0], s1[1]), fmaxf(s1[2], s1[3])), sh);
    float mx2 = block_red_max(fmaxf(fmaxf(s2[0], s2[1]), fmaxf(s2[2], s2[3])), sh);

    float e1[4], e2[4], z1 = 0.f, z2 = 0.f;
#pragma unroll
    for (int i = 0; i < 4; i++) {
        e1[i] = expf(s1[i] - mx1); z1 += e1[i];
        e2[i] = expf(s2[i] - mx2); z2 += e2[i];
    }
    float Z1 = block_red_sum(z1, sh);
    float Z2 = block_red_sum(z2, sh);

    float g = 1.f / (1.f + expf(-gating[0]));
    float c1 = (1.f - g) / Z1, c2 = (1.f - g) / Z2;

    float a1[4], a2[4], hh1 = 0.f, hh2 = 0.f;
#pragma unroll
    for (int i = 0; i < 4; i++) {
        a1[i] = e1[i] * c1 + g * p4[i];
        a2[i] = e2[i] * c2 + g * p4[i];
        hh1 -= a1[i] * logf(a1[i] + 1e-8f);
        hh2 -= a2[i] * logf(a2[i] + 1e-8f);
    }
    float H1 = block_red_sum(hh1, sh);
    float H2 = block_red_sum(hh2, sh);

    float tv = temp[0];
    float hm0 = 2.f - 2.f / (1.f + expf(-tv * H1));
    float hm1 = 2.f - 2.f / (1.f + expf(-tv * H2));
    int ks = (hm0 >= hm1) ? 0 : 1;
    if (t == 0) heat[bn] = ks ? hm1 : hm0;

    ushort4 w;
    w.x = f2bf(ks ? a2[0] : a1[0]);
    w.y = f2bf(ks ? a2[1] : a1[1]);
    w.z = f2bf(ks ? a2[2] : a1[2]);
    w.w = f2bf(ks ? a2[3] : a1[3]);
    *(ushort4*)s1p = w;   // attn_c (bf16 bits) over k=0 score plane
}

// ---------------------------------------------------------------------------
extern "C" void kernel_launch(void* const* d_in, const int* in_sizes, int n_in,
                              void* d_out, int out_size, void* d_ws, size_t ws_size,
                              hipStream_t stream)
{
    (void)in_sizes; (void)n_in; (void)out_size; (void)ws_size;
    const float* x      = (const float*)d_in[0];
    const float* y      = (const float*)d_in[1];
    const float* coords = (const float*)d_in[2];
    const float* U      = (const float*)d_in[3];
    const float* S1     = (const float*)d_in[4];
    const float* S2     = (const float*)d_in[5];
    const float* gating = (const float*)d_in[6];
    const float* temp   = (const float*)d_in[7];
    const float* pose   = (const float*)d_in[8];

    float* out  = (float*)d_out;
    float* heat = out + (long)BB * NN * DD;

    char* w = (char*)d_ws;
    u16* Ub  = (u16*)w;  w += (long)DD * DD * 2;            //  1.125 MB
    u16* VT  = (u16*)w;  w += (long)2 * DD * DD * 2;        //  2.25 MB (VT1,VT2)
    u16* xb  = (u16*)w;  w += (long)BB * NN * DD * 2;       // 24 MB
    u16* x12 = (u16*)w;  w += (long)2 * BB * NN * DD * 2;   // 48 MB
    u16* yb  = (u16*)w;  w += (long)BB * NN * DD * 2;       // 24 MB
    u16* yT  = (u16*)w;  w += (long)BB * DD * NN * 2;       // 24 MB
    u16* S   = (u16*)w;  w += (long)BB * 2 * NN * NN * 2;   // 64 MB
    float* P = (float*)w;                                   //  4 MB
    u16* xu  = S;   // xu [16384,768] bf16 aliases S (dead before S written)

    const long MBN = (long)BB * NN * DD;       // x1/x2 plane elements
    const long BND = (long)NN * DD;            // per-b x/y plane
    const long SPL = (long)NN * NN;            // score plane

    k_prep_u<<<dim3(24, 24), dim3(32, 8), 0, stream>>>(U, S1, S2, Ub, VT, VT + (long)DD * DD);
    k_conv_x<<<dim3(MBN / 2048), dim3(256), 0, stream>>>(x, xb);
    k_conv_y<<<dim3(DD / 32, NN / 32, BB), dim3(32, 8), 0, stream>>>(y, yb, yT);
    k_pos<<<dim3(NN), dim3(256), 0, stream>>>(coords, pose, P);

    // GEMM1: xu = xb @ U^T  (NT with B = Ub row-major)
    gemm128<0><<<dim3(BB * NN / 128, DD / 128, 1), dim3(256), 0, stream>>>(
        xb, Ub, xu, DD, DD, 1,
        0L, 0L, 0L, 0L, 0L, 0L, 1.0f);

    // GEMM2: x12[s] = xu @ (S_s^2 U)  (NT with B = VT_s); z = s
    gemm128<0><<<dim3(BB * NN / 128, DD / 128, 2), dim3(256), 0, stream>>>(
        xu, VT, x12, DD, DD, 2,
        0L, 0L, (long)DD * DD, 0L, MBN, 0L, 1.0f);

    // S[b,k] = scale * x_k[b] @ y[b]^T   (C f16); z = b*2 + k
    gemm128<1><<<dim3(NN / 128, NN / 128, BB * 2), dim3(256), 0, stream>>>(
        x12, yb, S, DD, NN, 2,
        MBN, BND, 0L, BND, SPL, 2 * SPL, 0.036084391824351615f);

    // softmax + blend + entropy + route; attn_c (bf16) in-place at k=0 plane
    k_route<<<dim3(BB * NN), dim3(256), 0, stream>>>(S, P, gating, temp, heat);

    // out[b] = attn_c[b] @ y[b]   (A bf16 in S k=0 plane, B = yT bf16, C f32)
    gemm128<2><<<dim3(NN / 128, DD / 128, BB), dim3(256), 0, stream>>>(
        S, yT, out, NN, DD, 1,
        0L, 2 * SPL, 0L, BND, 0L, BND, 1.0f);
}

// Round 4
// 400.199 us; speedup vs baseline: 3.0564x; 1.0778x over previous
//
#include <hip/hip_runtime.h>
#include <hip/hip_bf16.h>

#define DEV __device__ __forceinline__

typedef unsigned short u16;
typedef short short8 __attribute__((ext_vector_type(8)));
typedef float f32x4 __attribute__((ext_vector_type(4)));

static const int BB = 16;        // batch
static const int NN = 1024;      // tokens
static const int DD = 768;       // dim

DEV u16 f2bf(float f) {
    unsigned u = __builtin_bit_cast(unsigned, f);
    unsigned r = u + 0x7fffu + ((u >> 16) & 1u);
    return (u16)(r >> 16);
}
DEV float h2f(u16 u) { return (float)__builtin_bit_cast(_Float16, u); }
DEV u16 f2h(float f) { return __builtin_bit_cast(u16, (_Float16)f); }

DEV short8 ldf8_bf(const float* p) {
    float4 f0 = *(const float4*)p;
    float4 f1 = *(const float4*)(p + 4);
    short8 r;
    r[0] = (short)f2bf(f0.x); r[1] = (short)f2bf(f0.y);
    r[2] = (short)f2bf(f0.z); r[3] = (short)f2bf(f0.w);
    r[4] = (short)f2bf(f1.x); r[5] = (short)f2bf(f1.y);
    r[6] = (short)f2bf(f1.z); r[7] = (short)f2bf(f1.w);
    return r;
}

// async 16B global->LDS (direct-to-shared DMA); LDS dest = wave-uniform base + lane*16
DEV void gl_lds16(const u16* g, u16* l) {
    __builtin_amdgcn_global_load_lds(
        (const __attribute__((address_space(1))) unsigned int*)g,
        (__attribute__((address_space(3))) unsigned int*)l, 16, 0, 0);
}

// ---------------------------------------------------------------------------
// NT-GEMM: C[m,n] = scale * sum_k A[m,k]*B[n,k], A/B bf16 row-major.
// 128x128 tile, BK=64 (half the barrier drains of BK=32), 4 waves (2x2),
// each wave 4x4 mfma_f32_16x16x32_bf16, two sequential k-halves per K-tile
// (fragment regs stay at 32 VGPRs).
// LDS: As/Bs 128x64 bf16 (16KB each). 16B-chunk XOR swizzle q' = q ^ (row&7):
//   staging rows stay fully contiguous (128B/row), fragment ds_read_b128 lands
//   2 lanes/bank-group (free per m136).
// Batch z: off = (z%zmod)*s?0 + (z/zmod)*s?1 (element strides).
// OM: 0 = store bf16, 1 = store f16, 2 = store f32.
// ---------------------------------------------------------------------------
template<int OM>
__global__ __launch_bounds__(256) void gemm128(
    const u16* __restrict__ Ag, const u16* __restrict__ Bg, void* __restrict__ Cg,
    int K, int N, int zmod,
    long sA0, long sA1, long sB0, long sB1, long sC0, long sC1,
    float scale)
{
    __shared__ u16 As[128 * 64];
    __shared__ u16 Bs[128 * 64];

    int z = blockIdx.z;
    const u16* A = Ag + (long)(z % zmod) * sA0 + (long)(z / zmod) * sA1;
    const u16* B = Bg + (long)(z % zmod) * sB0 + (long)(z / zmod) * sB1;
    u16*   Cu = (u16*)Cg   + (long)(z % zmod) * sC0 + (long)(z / zmod) * sC1;
    float* Cf = (float*)Cg + (long)(z % zmod) * sC0 + (long)(z / zmod) * sC1;

    int tid  = threadIdx.x;
    int lane = tid & 63, wave = tid >> 6;
    int wm = wave & 1, wn = wave >> 1;
    int lr = lane & 15, quad = lane >> 4;

    long m0 = (long)blockIdx.x * 128;
    long n0 = (long)blockIdx.y * 128;

    // staging: 1024 16B-chunks per matrix; chunk position p -> row = p>>3,
    // slot qs = p&7 holds global chunk q = qs ^ (row&7). p = i*256 + tid
    // keeps LDS dest = uniform base + lane*16 per wave.
    long aOfs[4], bOfs[4];
    u16 *lA[4], *lB[4];
#pragma unroll
    for (int i = 0; i < 4; i++) {
        int p = tid + i * 256;
        int row = p >> 3, qs = p & 7;
        int q = qs ^ (row & 7);
        aOfs[i] = (m0 + row) * (long)K + q * 8;
        bOfs[i] = (n0 + row) * (long)K + q * 8;
        lA[i] = As + p * 8;
        lB[i] = Bs + p * 8;
    }

    // fragment LDS element offsets: row*64 + ((h*4+quad) ^ (row&7))*8
    int aoff[4][2], boff[4][2];
#pragma unroll
    for (int t = 0; t < 4; t++) {
        int ra = wm * 64 + t * 16 + lr;
        int rb = wn * 64 + t * 16 + lr;
#pragma unroll
        for (int h = 0; h < 2; h++) {
            aoff[t][h] = ra * 64 + (((h * 4 + quad) ^ (ra & 7)) * 8);
            boff[t][h] = rb * 64 + (((h * 4 + quad) ^ (rb & 7)) * 8);
        }
    }

    f32x4 acc[4][4] = {};

    for (int k0 = 0; k0 < K; k0 += 64) {
#pragma unroll
        for (int i = 0; i < 4; i++) gl_lds16(A + aOfs[i] + k0, lA[i]);
#pragma unroll
        for (int i = 0; i < 4; i++) gl_lds16(B + bOfs[i] + k0, lB[i]);
        __syncthreads();   // vmcnt(0) drain + barrier: staging visible

#pragma unroll
        for (int h = 0; h < 2; h++) {
            short8 af[4], bfr[4];
#pragma unroll
            for (int t = 0; t < 4; t++) af[t]  = *(const short8*)(As + aoff[t][h]);
#pragma unroll
            for (int t = 0; t < 4; t++) bfr[t] = *(const short8*)(Bs + boff[t][h]);
#pragma unroll
            for (int ti = 0; ti < 4; ti++)
#pragma unroll
                for (int tj = 0; tj < 4; tj++)
                    acc[ti][tj] = __builtin_amdgcn_mfma_f32_16x16x32_bf16(
                        af[ti], bfr[tj], acc[ti][tj], 0, 0, 0);
        }
        __syncthreads();   // protect LDS from next staging round
    }

    long crow = m0 + wm * 64 + quad * 4;
    long ccol = n0 + wn * 64 + lr;
#pragma unroll
    for (int ti = 0; ti < 4; ti++)
#pragma unroll
        for (int tj = 0; tj < 4; tj++)
#pragma unroll
            for (int r = 0; r < 4; r++) {
                long row = crow + ti * 16 + r;
                long col = ccol + tj * 16;
                float v = acc[ti][tj][r] * scale;
                long idx = row * (long)N + col;
                if constexpr (OM == 0)      Cu[idx] = f2bf(v);
                else if constexpr (OM == 1) Cu[idx] = f2h(v);
                else                        Cf[idx] = v;
            }
}

// ---------------------------------------------------------------------------
// Prep: UTb[j,i] = bf16(U[i,j]), VT_s[j,i] = bf16(S_s[i]^2 * U[i,j]).
// 32x32 LDS transpose tiles. grid (24,24), block (32,8).
// ---------------------------------------------------------------------------
__global__ __launch_bounds__(256) void k_prep_u(
    const float* __restrict__ U, const float* __restrict__ S1,
    const float* __restrict__ S2, u16* __restrict__ UTb,
    u16* __restrict__ VT1, u16* __restrict__ VT2)
{
    __shared__ float tile[32][33];
    int i0 = blockIdx.x * 32, j0 = blockIdx.y * 32;
#pragma unroll
    for (int r = 0; r < 32; r += 8) {
        int i = i0 + threadIdx.y + r, j = j0 + threadIdx.x;
        tile[threadIdx.y + r][threadIdx.x] = U[(long)i * DD + j];
    }
    __syncthreads();
    float s1v = S1[i0 + threadIdx.x];
    float s2v = S2[i0 + threadIdx.x];
    s1v *= s1v; s2v *= s2v;
#pragma unroll
    for (int r = 0; r < 32; r += 8) {
        int j = j0 + threadIdx.y + r, i = i0 + threadIdx.x;
        float v = tile[threadIdx.x][threadIdx.y + r];   // U[i][j]
        UTb[(long)j * DD + i] = f2bf(v);
        VT1[(long)j * DD + i] = f2bf(s1v * v);
        VT2[(long)j * DD + i] = f2bf(s2v * v);
    }
}

// ---------------------------------------------------------------------------
// x (f32) -> xb (bf16), flat. grid (MBN/2048), block 256, 8 elems/thread.
// ---------------------------------------------------------------------------
__global__ __launch_bounds__(256) void k_conv_x(
    const float* __restrict__ x, u16* __restrict__ xb)
{
    long i = ((long)blockIdx.x * 256 + threadIdx.x) * 8;
    *(short8*)(xb + i) = ldf8_bf(x + i);
}

// ---------------------------------------------------------------------------
// y -> yb (bf16, [b][m][d]) and yT (bf16, [b][d][m]) via 32x32 LDS transpose.
// grid (DD/32, NN/32, BB), block (32, 8)
// ---------------------------------------------------------------------------
__global__ __launch_bounds__(256) void k_conv_y(
    const float* __restrict__ y, u16* __restrict__ yb, u16* __restrict__ yT)
{
    __shared__ float tile[32][33];
    int b = blockIdx.z;
    int d0 = blockIdx.x * 32, m0 = blockIdx.y * 32;
    const float* ybase = y + (long)b * NN * DD;
#pragma unroll
    for (int r = 0; r < 32; r += 8) {
        int m = m0 + threadIdx.y + r, d = d0 + threadIdx.x;
        float v = ybase[(long)m * DD + d];
        tile[threadIdx.y + r][threadIdx.x] = v;
        yb[(long)b * NN * DD + (long)m * DD + d] = f2bf(v);
    }
    __syncthreads();
#pragma unroll
    for (int r = 0; r < 32; r += 8) {
        int d = d0 + threadIdx.y + r, m = m0 + threadIdx.x;
        yT[(long)b * DD * NN + (long)d * NN + m] = f2bf(tile[threadIdx.x][threadIdx.y + r]);
    }
}

// ---------------------------------------------------------------------------
// reductions (256 threads = 4 waves)
// ---------------------------------------------------------------------------
DEV float wave_red_max(float v) {
#pragma unroll
    for (int o = 32; o; o >>= 1) v = fmaxf(v, __shfl_xor(v, o));
    return v;
}
DEV float wave_red_sum(float v) {
#pragma unroll
    for (int o = 32; o; o >>= 1) v += __shfl_xor(v, o);
    return v;
}
DEV float block_red_max(float v, float* sh) {
    v = wave_red_max(v);
    if ((threadIdx.x & 63) == 0) sh[threadIdx.x >> 6] = v;
    __syncthreads();
    v = fmaxf(fmaxf(sh[0], sh[1]), fmaxf(sh[2], sh[3]));
    __syncthreads();
    return v;
}
DEV float block_red_sum(float v, float* sh) {
    v = wave_red_sum(v);
    if ((threadIdx.x & 63) == 0) sh[threadIdx.x >> 6] = v;
    __syncthreads();
    v = (sh[0] + sh[1]) + (sh[2] + sh[3]);
    __syncthreads();
    return v;
}

// ---------------------------------------------------------------------------
// P[n,m] = softmax_m( sum_c coords[n,m,c] * pos_emb[n,c] )   (fp32)
// grid (NN), block 256, 4 m per thread
// ---------------------------------------------------------------------------
__global__ __launch_bounds__(256) void k_pos(
    const float* __restrict__ coords, const float* __restrict__ pe,
    float* __restrict__ P)
{
    __shared__ float sh[4];
    int n = blockIdx.x, t = threadIdx.x;
    float p6[6];
#pragma unroll
    for (int c = 0; c < 6; c++) p6[c] = pe[n * 6 + c];
    float v[4];
#pragma unroll
    for (int i = 0; i < 4; i++) {
        const float* cp = coords + ((long)n * NN + t * 4 + i) * 6;
        v[i] = p6[0]*cp[0] + p6[1]*cp[1] + p6[2]*cp[2] + p6[3]*cp[3] + p6[4]*cp[4] + p6[5]*cp[5];
    }
    float mx = block_red_max(fmaxf(fmaxf(v[0], v[1]), fmaxf(v[2], v[3])), sh);
    float e[4], s = 0.f;
#pragma unroll
    for (int i = 0; i < 4; i++) { e[i] = expf(v[i] - mx); s += e[i]; }
    float Z = block_red_sum(s, sh);
    float inv = 1.f / Z;
    float4 o; o.x = e[0]*inv; o.y = e[1]*inv; o.z = e[2]*inv; o.w = e[3]*inv;
    *(float4*)(P + ((long)n << 10) + t * 4) = o;
}

// ---------------------------------------------------------------------------
// Per (b,n) row: softmax both k, blend with pos, entropy, route, write heat
// and selected blended attn row (bf16 bits) IN-PLACE over S plane k=0.
// grid (B*N), block 256, 4 m per thread per k.
// ---------------------------------------------------------------------------
__global__ __launch_bounds__(256) void k_route(
    u16* __restrict__ S, const float* __restrict__ P,
    const float* __restrict__ gating, const float* __restrict__ temp,
    float* __restrict__ heat)
{
    __shared__ float sh[4];
    int bn = blockIdx.x;
    int b = bn >> 10, n = bn & 1023, t = threadIdx.x;
    u16* s1p = S + ((long)(b * 2) << 20) + ((long)n << 10) + t * 4;
    u16* s2p = s1p + (1L << 20);
    const float* pp = P + ((long)n << 10) + t * 4;

    ushort4 r1 = *(const ushort4*)s1p;
    ushort4 r2 = *(const ushort4*)s2p;
    float4 pv = *(const float4*)pp;
    float s1[4] = { h2f(r1.x), h2f(r1.y), h2f(r1.z), h2f(r1.w) };
    float s2[4] = { h2f(r2.x), h2f(r2.y), h2f(r2.z), h2f(r2.w) };
    float p4[4] = { pv.x, pv.y, pv.z, pv.w };

    float mx1 = block_red_max(fmaxf(fmaxf(s1[0], s1[1]), fmaxf(s1[2], s1[3])), sh);
    float mx2 = block_red_max(fmaxf(fmaxf(s2[0], s2[1]), fmaxf(s2[2], s2[3])), sh);

    float e1[4], e2[4], z1 = 0.f, z2 = 0.f;
#pragma unroll
    for (int i = 0; i < 4; i++) {
        e1[i] = expf(s1[i] - mx1); z1 += e1[i];
        e2[i] = expf(s2[i] - mx2); z2 += e2[i];
    }
    float Z1 = block_red_sum(z1, sh);
    float Z2 = block_red_sum(z2, sh);

    float g = 1.f / (1.f + expf(-gating[0]));
    float c1 = (1.f - g) / Z1, c2 = (1.f - g) / Z2;

    float a1[4], a2[4], hh1 = 0.f, hh2 = 0.f;
#pragma unroll
    for (int i = 0; i < 4; i++) {
        a1[i] = e1[i] * c1 + g * p4[i];
        a2[i] = e2[i] * c2 + g * p4[i];
        hh1 -= a1[i] * logf(a1[i] + 1e-8f);
        hh2 -= a2[i] * logf(a2[i] + 1e-8f);
    }
    float H1 = block_red_sum(hh1, sh);
    float H2 = block_red_sum(hh2, sh);

    float tv = temp[0];
    float hm0 = 2.f - 2.f / (1.f + expf(-tv * H1));
    float hm1 = 2.f - 2.f / (1.f + expf(-tv * H2));
    int ks = (hm0 >= hm1) ? 0 : 1;
    if (t == 0) heat[bn] = ks ? hm1 : hm0;

    ushort4 w;
    w.x = f2bf(ks ? a2[0] : a1[0]);
    w.y = f2bf(ks ? a2[1] : a1[1]);
    w.z = f2bf(ks ? a2[2] : a1[2]);
    w.w = f2bf(ks ? a2[3] : a1[3]);
    *(ushort4*)s1p = w;   // attn_c (bf16 bits) over k=0 score plane
}

// ---------------------------------------------------------------------------
extern "C" void kernel_launch(void* const* d_in, const int* in_sizes, int n_in,
                              void* d_out, int out_size, void* d_ws, size_t ws_size,
                              hipStream_t stream)
{
    (void)in_sizes; (void)n_in; (void)out_size; (void)ws_size;
    const float* x      = (const float*)d_in[0];
    const float* y      = (const float*)d_in[1];
    const float* coords = (const float*)d_in[2];
    const float* U      = (const float*)d_in[3];
    const float* S1     = (const float*)d_in[4];
    const float* S2     = (const float*)d_in[5];
    const float* gating = (const float*)d_in[6];
    const float* temp   = (const float*)d_in[7];
    const float* pose   = (const float*)d_in[8];

    float* out  = (float*)d_out;
    float* heat = out + (long)BB * NN * DD;

    char* w = (char*)d_ws;
    u16* UTb = (u16*)w;  w += (long)DD * DD * 2;            //  1.125 MB
    u16* VT  = (u16*)w;  w += (long)2 * DD * DD * 2;        //  2.25 MB (VT1,VT2)
    u16* W2  = (u16*)w;  w += (long)2 * DD * DD * 2;        //  2.25 MB (W1,W2)
    u16* xb  = (u16*)w;  w += (long)BB * NN * DD * 2;       // 24 MB
    u16* x12 = (u16*)w;  w += (long)2 * BB * NN * DD * 2;   // 48 MB
    u16* yb  = (u16*)w;  w += (long)BB * NN * DD * 2;       // 24 MB
    u16* yT  = (u16*)w;  w += (long)BB * DD * NN * 2;       // 24 MB
    u16* S   = (u16*)w;  w += (long)BB * 2 * NN * NN * 2;   // 64 MB
    float* P = (float*)w;                                   //  4 MB

    const long MBN = (long)BB * NN * DD;       // x1/x2 plane elements
    const long BND = (long)NN * DD;            // per-b x/y plane
    const long SPL = (long)NN * NN;            // score plane
    const long DSQ = (long)DD * DD;

    k_prep_u<<<dim3(24, 24), dim3(32, 8), 0, stream>>>(U, S1, S2, UTb, VT, VT + DSQ);
    k_conv_x<<<dim3(MBN / 2048), dim3(256), 0, stream>>>(x, xb);
    k_conv_y<<<dim3(DD / 32, NN / 32, BB), dim3(32, 8), 0, stream>>>(y, yb, yT);
    k_pos<<<dim3(NN), dim3(256), 0, stream>>>(coords, pose, P);

    // W_s[i,j] = sum_t U[t,i] S_s[t]^2 U[t,j]  (NT: A=UTb, B=VT_s); z = s
    gemm128<0><<<dim3(DD / 128, DD / 128, 2), dim3(256), 0, stream>>>(
        UTb, VT, W2, DD, DD, 2,
        0L, 0L, DSQ, 0L, DSQ, 0L, 1.0f);

    // x12[s] = xb @ W_s  (NT: B = W_s row-major, W symmetric); z = s
    gemm128<0><<<dim3(BB * NN / 128, DD / 128, 2), dim3(256), 0, stream>>>(
        xb, W2, x12, DD, DD, 2,
        0L, 0L, DSQ, 0L, MBN, 0L, 1.0f);

    // S[b,k] = scale * x_k[b] @ y[b]^T   (C f16); z = b*2 + k
    gemm128<1><<<dim3(NN / 128, NN / 128, BB * 2), dim3(256), 0, stream>>>(
        x12, yb, S, DD, NN, 2,
        MBN, BND, 0L, BND, SPL, 2 * SPL, 0.036084391824351615f);

    // softmax + blend + entropy + route; attn_c (bf16) in-place at k=0 plane
    k_route<<<dim3(BB * NN), dim3(256), 0, stream>>>(S, P, gating, temp, heat);

    // out[b] = attn_c[b] @ y[b]   (A bf16 in S k=0 plane, B = yT bf16, C f32)
    gemm128<2><<<dim3(NN / 128, DD / 128, BB), dim3(256), 0, stream>>>(
        S, yT, out, NN, DD, 1,
        0L, 2 * SPL, 0L, BND, 0L, BND, 1.0f);
}

// Round 5
// 384.570 us; speedup vs baseline: 3.1806x; 1.0406x over previous
//
#include <hip/hip_runtime.h>
#include <hip/hip_bf16.h>

#define DEV __device__ __forceinline__

typedef unsigned short u16;
typedef short short8 __attribute__((ext_vector_type(8)));
typedef float f32x16 __attribute__((ext_vector_type(16)));

static const int BB = 16;        // batch
static const int NN = 1024;      // tokens
static const int DD = 768;       // dim

DEV u16 f2bf(float f) {
    unsigned u = __builtin_bit_cast(unsigned, f);
    unsigned r = u + 0x7fffu + ((u >> 16) & 1u);
    return (u16)(r >> 16);
}
DEV float h2f(u16 u) { return (float)__builtin_bit_cast(_Float16, u); }
DEV u16 f2h(float f) { return __builtin_bit_cast(u16, (_Float16)f); }

DEV short8 ldf8_bf(const float* p) {
    float4 f0 = *(const float4*)p;
    float4 f1 = *(const float4*)(p + 4);
    short8 r;
    r[0] = (short)f2bf(f0.x); r[1] = (short)f2bf(f0.y);
    r[2] = (short)f2bf(f0.z); r[3] = (short)f2bf(f0.w);
    r[4] = (short)f2bf(f1.x); r[5] = (short)f2bf(f1.y);
    r[6] = (short)f2bf(f1.z); r[7] = (short)f2bf(f1.w);
    return r;
}

// async 16B global->LDS (direct-to-shared DMA); LDS dest = wave-uniform base + lane*16
DEV void gl_lds16(const u16* g, u16* l) {
    __builtin_amdgcn_global_load_lds(
        (const __attribute__((address_space(1))) unsigned int*)g,
        (__attribute__((address_space(3))) unsigned int*)l, 16, 0, 0);
}

// ---------------------------------------------------------------------------
// NT-GEMM: C[m,n] = scale * sum_k A[m,k]*B[n,k], A/B bf16 row-major.
// 128x128 tile, BK=64, 4 waves (2x2). Wave tile 64x64 = 2x2 of
// mfma_f32_32x32x16_bf16 (half the MFMA instr count of 16x16x32; ~17% fewer
// matrix-pipe cycles at m119 rates; frag regs 32->16 VGPRs).
// LDS: As/Bs 128x64 bf16 (16KB each), 16B-chunk XOR swizzle slot = q ^ (row&7):
//   staging rows fully contiguous (128B/row), fragment ds_read_b128 conflict-free.
// A-frag: A[m=lane&31][k=(lane>>5)*8+j]; C/D: col=lane&31,
// row=(reg&3)+8*(reg>>2)+4*(lane>>5)  [m74/m101-verified mapping].
// Batch z: off = (z%zmod)*s?0 + (z/zmod)*s?1 (element strides).
// OM: 0 = store bf16, 1 = store f16, 2 = store f32.
// ---------------------------------------------------------------------------
template<int OM>
__global__ __launch_bounds__(256, 3) void gemm128(
    const u16* __restrict__ Ag, const u16* __restrict__ Bg, void* __restrict__ Cg,
    int K, int N, int zmod,
    long sA0, long sA1, long sB0, long sB1, long sC0, long sC1,
    float scale)
{
    __shared__ u16 As[128 * 64];
    __shared__ u16 Bs[128 * 64];

    int z = blockIdx.z;
    const u16* A = Ag + (long)(z % zmod) * sA0 + (long)(z / zmod) * sA1;
    const u16* B = Bg + (long)(z % zmod) * sB0 + (long)(z / zmod) * sB1;
    u16*   Cu = (u16*)Cg   + (long)(z % zmod) * sC0 + (long)(z / zmod) * sC1;
    float* Cf = (float*)Cg + (long)(z % zmod) * sC0 + (long)(z / zmod) * sC1;

    int tid  = threadIdx.x;
    int lane = tid & 63, wave = tid >> 6;
    int wm = wave & 1, wn = wave >> 1;
    int ln31 = lane & 31, khalf = lane >> 5;

    long m0 = (long)blockIdx.x * 128;
    long n0 = (long)blockIdx.y * 128;

    // staging: 1024 16B-chunks per matrix; position p -> row = p>>3, slot
    // qs = p&7 holds global chunk q = qs ^ (row&7). p = i*256 + tid keeps
    // LDS dest = uniform base + lane*16 per wave.
    long aOfs[4], bOfs[4];
    u16 *lA[4], *lB[4];
#pragma unroll
    for (int i = 0; i < 4; i++) {
        int p = tid + i * 256;
        int row = p >> 3, qs = p & 7;
        int q = qs ^ (row & 7);
        aOfs[i] = (m0 + row) * (long)K + q * 8;
        bOfs[i] = (n0 + row) * (long)K + q * 8;
        lA[i] = As + p * 8;
        lB[i] = Bs + p * 8;
    }

    // fragment LDS element offsets: row*64 + ((h*2+khalf) ^ (row&7))*8
    int aoff[2][4], boff[2][4];
#pragma unroll
    for (int t = 0; t < 2; t++) {
        int ra = wm * 64 + t * 32 + ln31;
        int rb = wn * 64 + t * 32 + ln31;
#pragma unroll
        for (int h = 0; h < 4; h++) {
            aoff[t][h] = ra * 64 + (((h * 2 + khalf) ^ (ra & 7)) * 8);
            boff[t][h] = rb * 64 + (((h * 2 + khalf) ^ (rb & 7)) * 8);
        }
    }

    f32x16 acc[2][2] = {};

    for (int k0 = 0; k0 < K; k0 += 64) {
#pragma unroll
        for (int i = 0; i < 4; i++) gl_lds16(A + aOfs[i] + k0, lA[i]);
#pragma unroll
        for (int i = 0; i < 4; i++) gl_lds16(B + bOfs[i] + k0, lB[i]);
        __syncthreads();   // vmcnt(0) drain + barrier: staging visible

#pragma unroll
        for (int h = 0; h < 4; h++) {
            short8 af[2], bfr[2];
#pragma unroll
            for (int t = 0; t < 2; t++) af[t]  = *(const short8*)(As + aoff[t][h]);
#pragma unroll
            for (int t = 0; t < 2; t++) bfr[t] = *(const short8*)(Bs + boff[t][h]);
#pragma unroll
            for (int ti = 0; ti < 2; ti++)
#pragma unroll
                for (int tj = 0; tj < 2; tj++)
                    acc[ti][tj] = __builtin_amdgcn_mfma_f32_32x32x16_bf16(
                        af[ti], bfr[tj], acc[ti][tj], 0, 0, 0);
        }
        __syncthreads();   // protect LDS from next staging round
    }

    long crow = m0 + wm * 64 + 4 * khalf;
    long ccol = n0 + wn * 64 + ln31;
#pragma unroll
    for (int ti = 0; ti < 2; ti++)
#pragma unroll
        for (int tj = 0; tj < 2; tj++)
#pragma unroll
            for (int r = 0; r < 16; r++) {
                long row = crow + ti * 32 + (r & 3) + 8 * (r >> 2);
                long col = ccol + tj * 32;
                float v = acc[ti][tj][r] * scale;
                long idx = row * (long)N + col;
                if constexpr (OM == 0)      Cu[idx] = f2bf(v);
                else if constexpr (OM == 1) Cu[idx] = f2h(v);
                else                        Cf[idx] = v;
            }
}

// ---------------------------------------------------------------------------
// reductions (256 threads = 4 waves)
// ---------------------------------------------------------------------------
DEV float wave_red_max(float v) {
#pragma unroll
    for (int o = 32; o; o >>= 1) v = fmaxf(v, __shfl_xor(v, o));
    return v;
}
DEV float wave_red_sum(float v) {
#pragma unroll
    for (int o = 32; o; o >>= 1) v += __shfl_xor(v, o);
    return v;
}
DEV float block_red_max(float v, float* sh) {
    v = wave_red_max(v);
    if ((threadIdx.x & 63) == 0) sh[threadIdx.x >> 6] = v;
    __syncthreads();
    v = fmaxf(fmaxf(sh[0], sh[1]), fmaxf(sh[2], sh[3]));
    __syncthreads();
    return v;
}
DEV float block_red_sum(float v, float* sh) {
    v = wave_red_sum(v);
    if ((threadIdx.x & 63) == 0) sh[threadIdx.x >> 6] = v;
    __syncthreads();
    v = (sh[0] + sh[1]) + (sh[2] + sh[3]);
    __syncthreads();
    return v;
}

// ---------------------------------------------------------------------------
// Fused prep: one flat grid, 256-thread blocks, block ranges do:
//   [0, 6144)           conv_x : xb = bf16(x), 8 elems/thread
//   [6144, 18432)       conv_y : yb = bf16(y); yT = bf16(y^T) via 32x32 tile
//   [18432, 19456)      pos    : P[n,:] = softmax(coords[n] @ pos_emb[n])
//   [19456, 20032)      prep_u : UTb = bf16(U^T), VT_s = bf16(S_s^2 * U)^T
// Removes 3 serial dispatch boundaries from the graph chain.
// ---------------------------------------------------------------------------
__global__ __launch_bounds__(256) void k_prep_all(
    const float* __restrict__ x, const float* __restrict__ y,
    const float* __restrict__ coords, const float* __restrict__ U,
    const float* __restrict__ S1, const float* __restrict__ S2,
    const float* __restrict__ pe,
    u16* __restrict__ xb, u16* __restrict__ yb, u16* __restrict__ yT,
    u16* __restrict__ UTb, u16* __restrict__ VT1, u16* __restrict__ VT2,
    float* __restrict__ P)
{
    __shared__ float shmem[32 * 33];
    int bid = blockIdx.x, tid = threadIdx.x;

    if (bid < 6144) {                          // ---- conv_x
        long i = ((long)bid * 256 + tid) * 8;
        *(short8*)(xb + i) = ldf8_bf(x + i);
        return;
    }
    bid -= 6144;

    if (bid < 12288) {                         // ---- conv_y
        float (*tile)[33] = (float(*)[33])shmem;
        int b = bid / 768, rem = bid % 768;
        int d0 = (rem % 24) * 32, m0 = (rem / 24) * 32;
        int tx = tid & 31, ty = tid >> 5;
        const float* ybase = y + (long)b * NN * DD;
#pragma unroll
        for (int r = 0; r < 32; r += 8) {
            int m = m0 + ty + r, d = d0 + tx;
            float v = ybase[(long)m * DD + d];
            tile[ty + r][tx] = v;
            yb[(long)b * NN * DD + (long)m * DD + d] = f2bf(v);
        }
        __syncthreads();
#pragma unroll
        for (int r = 0; r < 32; r += 8) {
            int d = d0 + ty + r, m = m0 + tx;
            yT[(long)b * DD * NN + (long)d * NN + m] = f2bf(tile[tx][ty + r]);
        }
        return;
    }
    bid -= 12288;

    if (bid < 1024) {                          // ---- pos
        int n = bid, t = tid;
        float p6[6];
#pragma unroll
        for (int c = 0; c < 6; c++) p6[c] = pe[n * 6 + c];
        float v[4];
#pragma unroll
        for (int i = 0; i < 4; i++) {
            const float* cp = coords + ((long)n * NN + t * 4 + i) * 6;
            v[i] = p6[0]*cp[0] + p6[1]*cp[1] + p6[2]*cp[2]
                 + p6[3]*cp[3] + p6[4]*cp[4] + p6[5]*cp[5];
        }
        float mx = block_red_max(fmaxf(fmaxf(v[0], v[1]), fmaxf(v[2], v[3])), shmem);
        float e[4], s = 0.f;
#pragma unroll
        for (int i = 0; i < 4; i++) { e[i] = expf(v[i] - mx); s += e[i]; }
        float Z = block_red_sum(s, shmem);
        float inv = 1.f / Z;
        float4 o; o.x = e[0]*inv; o.y = e[1]*inv; o.z = e[2]*inv; o.w = e[3]*inv;
        *(float4*)(P + ((long)n << 10) + t * 4) = o;
        return;
    }
    bid -= 1024;

    {                                          // ---- prep_u (576 blocks)
        float (*tile)[33] = (float(*)[33])shmem;
        int i0 = (bid % 24) * 32, j0 = (bid / 24) * 32;
        int tx = tid & 31, ty = tid >> 5;
#pragma unroll
        for (int r = 0; r < 32; r += 8) {
            int i = i0 + ty + r, j = j0 + tx;
            tile[ty + r][tx] = U[(long)i * DD + j];
        }
        __syncthreads();
        float s1v = S1[i0 + tx];
        float s2v = S2[i0 + tx];
        s1v *= s1v; s2v *= s2v;
#pragma unroll
        for (int r = 0; r < 32; r += 8) {
            int j = j0 + ty + r, i = i0 + tx;
            float v = tile[tx][ty + r];   // U[i][j]
            UTb[(long)j * DD + i] = f2bf(v);
            VT1[(long)j * DD + i] = f2bf(s1v * v);
            VT2[(long)j * DD + i] = f2bf(s2v * v);
        }
    }
}

// ---------------------------------------------------------------------------
// Per (b,n) row: softmax both k, blend with pos, entropy, route, write heat
// and selected blended attn row (bf16 bits) IN-PLACE over S plane k=0.
// grid (B*N), block 256, 4 m per thread per k.
// ---------------------------------------------------------------------------
__global__ __launch_bounds__(256) void k_route(
    u16* __restrict__ S, const float* __restrict__ P,
    const float* __restrict__ gating, const float* __restrict__ temp,
    float* __restrict__ heat)
{
    __shared__ float sh[4];
    int bn = blockIdx.x;
    int b = bn >> 10, n = bn & 1023, t = threadIdx.x;
    u16* s1p = S + ((long)(b * 2) << 20) + ((long)n << 10) + t * 4;
    u16* s2p = s1p + (1L << 20);
    const float* pp = P + ((long)n << 10) + t * 4;

    ushort4 r1 = *(const ushort4*)s1p;
    ushort4 r2 = *(const ushort4*)s2p;
    float4 pv = *(const float4*)pp;
    float s1[4] = { h2f(r1.x), h2f(r1.y), h2f(r1.z), h2f(r1.w) };
    float s2[4] = { h2f(r2.x), h2f(r2.y), h2f(r2.z), h2f(r2.w) };
    float p4[4] = { pv.x, pv.y, pv.z, pv.w };

    float mx1 = block_red_max(fmaxf(fmaxf(s1[0], s1[1]), fmaxf(s1[2], s1[3])), sh);
    float mx2 = block_red_max(fmaxf(fmaxf(s2[0], s2[1]), fmaxf(s2[2], s2[3])), sh);

    float e1[4], e2[4], z1 = 0.f, z2 = 0.f;
#pragma unroll
    for (int i = 0; i < 4; i++) {
        e1[i] = expf(s1[i] - mx1); z1 += e1[i];
        e2[i] = expf(s2[i] - mx2); z2 += e2[i];
    }
    float Z1 = block_red_sum(z1, sh);
    float Z2 = block_red_sum(z2, sh);

    float g = 1.f / (1.f + expf(-gating[0]));
    float c1 = (1.f - g) / Z1, c2 = (1.f - g) / Z2;

    float a1[4], a2[4], hh1 = 0.f, hh2 = 0.f;
#pragma unroll
    for (int i = 0; i < 4; i++) {
        a1[i] = e1[i] * c1 + g * p4[i];
        a2[i] = e2[i] * c2 + g * p4[i];
        hh1 -= a1[i] * logf(a1[i] + 1e-8f);
        hh2 -= a2[i] * logf(a2[i] + 1e-8f);
    }
    float H1 = block_red_sum(hh1, sh);
    float H2 = block_red_sum(hh2, sh);

    float tv = temp[0];
    float hm0 = 2.f - 2.f / (1.f + expf(-tv * H1));
    float hm1 = 2.f - 2.f / (1.f + expf(-tv * H2));
    int ks = (hm0 >= hm1) ? 0 : 1;
    if (t == 0) heat[bn] = ks ? hm1 : hm0;

    ushort4 w;
    w.x = f2bf(ks ? a2[0] : a1[0]);
    w.y = f2bf(ks ? a2[1] : a1[1]);
    w.z = f2bf(ks ? a2[2] : a1[2]);
    w.w = f2bf(ks ? a2[3] : a1[3]);
    *(ushort4*)s1p = w;   // attn_c (bf16 bits) over k=0 score plane
}

// ---------------------------------------------------------------------------
extern "C" void kernel_launch(void* const* d_in, const int* in_sizes, int n_in,
                              void* d_out, int out_size, void* d_ws, size_t ws_size,
                              hipStream_t stream)
{
    (void)in_sizes; (void)n_in; (void)out_size; (void)ws_size;
    const float* x      = (const float*)d_in[0];
    const float* y      = (const float*)d_in[1];
    const float* coords = (const float*)d_in[2];
    const float* U      = (const float*)d_in[3];
    const float* S1     = (const float*)d_in[4];
    const float* S2     = (const float*)d_in[5];
    const float* gating = (const float*)d_in[6];
    const float* temp   = (const float*)d_in[7];
    const float* pose   = (const float*)d_in[8];

    float* out  = (float*)d_out;
    float* heat = out + (long)BB * NN * DD;

    char* w = (char*)d_ws;
    u16* UTb = (u16*)w;  w += (long)DD * DD * 2;            //  1.125 MB
    u16* VT  = (u16*)w;  w += (long)2 * DD * DD * 2;        //  2.25 MB (VT1,VT2)
    u16* W2  = (u16*)w;  w += (long)2 * DD * DD * 2;        //  2.25 MB (W1,W2)
    u16* xb  = (u16*)w;  w += (long)BB * NN * DD * 2;       // 24 MB
    u16* x12 = (u16*)w;  w += (long)2 * BB * NN * DD * 2;   // 48 MB
    u16* yb  = (u16*)w;  w += (long)BB * NN * DD * 2;       // 24 MB
    u16* yT  = (u16*)w;  w += (long)BB * DD * NN * 2;       // 24 MB
    u16* S   = (u16*)w;  w += (long)BB * 2 * NN * NN * 2;   // 64 MB
    float* P = (float*)w;                                   //  4 MB

    const long MBN = (long)BB * NN * DD;       // x1/x2 plane elements
    const long BND = (long)NN * DD;            // per-b x/y plane
    const long SPL = (long)NN * NN;            // score plane
    const long DSQ = (long)DD * DD;

    // fused prep: conv_x | conv_y | pos | prep_u
    k_prep_all<<<dim3(20032), dim3(256), 0, stream>>>(
        x, y, coords, U, S1, S2, pose, xb, yb, yT, UTb, VT, VT + DSQ, P);

    // W_s[i,j] = sum_t U[t,i] S_s[t]^2 U[t,j]  (NT: A=UTb, B=VT_s); z = s
    gemm128<0><<<dim3(DD / 128, DD / 128, 2), dim3(256), 0, stream>>>(
        UTb, VT, W2, DD, DD, 2,
        0L, 0L, DSQ, 0L, DSQ, 0L, 1.0f);

    // x12[s] = xb @ W_s  (NT: B = W_s row-major, W symmetric); z = s
    gemm128<0><<<dim3(BB * NN / 128, DD / 128, 2), dim3(256), 0, stream>>>(
        xb, W2, x12, DD, DD, 2,
        0L, 0L, DSQ, 0L, MBN, 0L, 1.0f);

    // S[b,k] = scale * x_k[b] @ y[b]^T   (C f16); z = b*2 + k
    gemm128<1><<<dim3(NN / 128, NN / 128, BB * 2), dim3(256), 0, stream>>>(
        x12, yb, S, DD, NN, 2,
        MBN, BND, 0L, BND, SPL, 2 * SPL, 0.036084391824351615f);

    // softmax + blend + entropy + route; attn_c (bf16) in-place at k=0 plane
    k_route<<<dim3(BB * NN), dim3(256), 0, stream>>>(S, P, gating, temp, heat);

    // out[b] = attn_c[b] @ y[b]   (A bf16 in S k=0 plane, B = yT bf16, C f32)
    gemm128<2><<<dim3(NN / 128, DD / 128, BB), dim3(256), 0, stream>>>(
        S, yT, out, NN, DD, 1,
        0L, 2 * SPL, 0L, BND, 0L, BND, 1.0f);
}

// Round 6
// 370.214 us; speedup vs baseline: 3.3040x; 1.0388x over previous
//
#include <hip/hip_runtime.h>
#include <hip/hip_bf16.h>

#define DEV __device__ __forceinline__

typedef unsigned short u16;
typedef short short8 __attribute__((ext_vector_type(8)));
typedef float f32x16 __attribute__((ext_vector_type(16)));

static const int BB = 16;        // batch
static const int NN = 1024;      // tokens
static const int DD = 768;       // dim

DEV u16 f2bf(float f) {
    unsigned u = __builtin_bit_cast(unsigned, f);
    unsigned r = u + 0x7fffu + ((u >> 16) & 1u);
    return (u16)(r >> 16);
}
DEV float h2f(u16 u) { return (float)__builtin_bit_cast(_Float16, u); }
DEV u16 f2h(float f) { return __builtin_bit_cast(u16, (_Float16)f); }

DEV short8 ldf8_bf(const float* p) {
    float4 f0 = *(const float4*)p;
    float4 f1 = *(const float4*)(p + 4);
    short8 r;
    r[0] = (short)f2bf(f0.x); r[1] = (short)f2bf(f0.y);
    r[2] = (short)f2bf(f0.z); r[3] = (short)f2bf(f0.w);
    r[4] = (short)f2bf(f1.x); r[5] = (short)f2bf(f1.y);
    r[6] = (short)f2bf(f1.z); r[7] = (short)f2bf(f1.w);
    return r;
}

// async 16B global->LDS (direct-to-shared DMA); LDS dest = wave-uniform base + lane*16
DEV void gl_lds16(const void* g, void* l) {
    __builtin_amdgcn_global_load_lds(
        (const __attribute__((address_space(1))) unsigned int*)g,
        (__attribute__((address_space(3))) unsigned int*)l, 16, 0, 0);
}

// pack hi16 of two f32 -> (bf16 f0 | bf16 f1 << 16), RTZ, single v_perm_b32
DEV unsigned pkbf_rtz(float f0, float f1) {
    return __builtin_amdgcn_perm(__builtin_bit_cast(unsigned, f1),
                                 __builtin_bit_cast(unsigned, f0), 0x07060302u);
}

// ---------------------------------------------------------------------------
// NT-GEMM: C[m,n] = scale * sum_k A[m,k]*B[n,k], A/B bf16 row-major.
// 128x128 tile, BK=64, 4 waves (2x2). Wave tile 64x64 = 2x2 of
// mfma_f32_32x32x16_bf16. LDS: As/Bs 128x64 bf16 (16KB each), 16B-chunk XOR
// swizzle slot = q ^ (row&7). SQ_LDS_BANK_CONFLICT ~6.3M here is cross-block
// (staging DMA vs fragment reads at 3 blocks/CU) — benign, R5 A/B showed net win.
// OM: 0 = store bf16, 1 = store f16, 2 = store f32.
// ---------------------------------------------------------------------------
template<int OM>
__global__ __launch_bounds__(256, 3) void gemm128(
    const u16* __restrict__ Ag, const u16* __restrict__ Bg, void* __restrict__ Cg,
    int K, int N, int zmod,
    long sA0, long sA1, long sB0, long sB1, long sC0, long sC1,
    float scale)
{
    __shared__ u16 As[128 * 64];
    __shared__ u16 Bs[128 * 64];

    int z = blockIdx.z;
    const u16* A = Ag + (long)(z % zmod) * sA0 + (long)(z / zmod) * sA1;
    const u16* B = Bg + (long)(z % zmod) * sB0 + (long)(z / zmod) * sB1;
    u16*   Cu = (u16*)Cg   + (long)(z % zmod) * sC0 + (long)(z / zmod) * sC1;
    float* Cf = (float*)Cg + (long)(z % zmod) * sC0 + (long)(z / zmod) * sC1;

    int tid  = threadIdx.x;
    int lane = tid & 63, wave = tid >> 6;
    int wm = wave & 1, wn = wave >> 1;
    int ln31 = lane & 31, khalf = lane >> 5;

    long m0 = (long)blockIdx.x * 128;
    long n0 = (long)blockIdx.y * 128;

    long aOfs[4], bOfs[4];
    u16 *lA[4], *lB[4];
#pragma unroll
    for (int i = 0; i < 4; i++) {
        int p = tid + i * 256;
        int row = p >> 3, qs = p & 7;
        int q = qs ^ (row & 7);
        aOfs[i] = (m0 + row) * (long)K + q * 8;
        bOfs[i] = (n0 + row) * (long)K + q * 8;
        lA[i] = As + p * 8;
        lB[i] = Bs + p * 8;
    }

    int aoff[2][4], boff[2][4];
#pragma unroll
    for (int t = 0; t < 2; t++) {
        int ra = wm * 64 + t * 32 + ln31;
        int rb = wn * 64 + t * 32 + ln31;
#pragma unroll
        for (int h = 0; h < 4; h++) {
            aoff[t][h] = ra * 64 + (((h * 2 + khalf) ^ (ra & 7)) * 8);
            boff[t][h] = rb * 64 + (((h * 2 + khalf) ^ (rb & 7)) * 8);
        }
    }

    f32x16 acc[2][2] = {};

    for (int k0 = 0; k0 < K; k0 += 64) {
#pragma unroll
        for (int i = 0; i < 4; i++) gl_lds16(A + aOfs[i] + k0, lA[i]);
#pragma unroll
        for (int i = 0; i < 4; i++) gl_lds16(B + bOfs[i] + k0, lB[i]);
        __syncthreads();

#pragma unroll
        for (int h = 0; h < 4; h++) {
            short8 af[2], bfr[2];
#pragma unroll
            for (int t = 0; t < 2; t++) af[t]  = *(const short8*)(As + aoff[t][h]);
#pragma unroll
            for (int t = 0; t < 2; t++) bfr[t] = *(const short8*)(Bs + boff[t][h]);
#pragma unroll
            for (int ti = 0; ti < 2; ti++)
#pragma unroll
                for (int tj = 0; tj < 2; tj++)
                    acc[ti][tj] = __builtin_amdgcn_mfma_f32_32x32x16_bf16(
                        af[ti], bfr[tj], acc[ti][tj], 0, 0, 0);
        }
        __syncthreads();
    }

    long crow = m0 + wm * 64 + 4 * khalf;
    long ccol = n0 + wn * 64 + ln31;
#pragma unroll
    for (int ti = 0; ti < 2; ti++)
#pragma unroll
        for (int tj = 0; tj < 2; tj++)
#pragma unroll
            for (int r = 0; r < 16; r++) {
                long row = crow + ti * 32 + (r & 3) + 8 * (r >> 2);
                long col = ccol + tj * 32;
                float v = acc[ti][tj][r] * scale;
                long idx = row * (long)N + col;
                if constexpr (OM == 0)      Cu[idx] = f2bf(v);
                else if constexpr (OM == 1) Cu[idx] = f2h(v);
                else                        Cf[idx] = v;
            }
}

// ---------------------------------------------------------------------------
// Same GEMM but A is f32 row-major, staged to LDS as f32 (32KB) and converted
// to bf16 (RTZ via v_perm_b32) at fragment read. B bf16. C bf16. A shared
// across z; B/C strided by z. Deletes the conv_x pre-pass.
// ---------------------------------------------------------------------------
__global__ __launch_bounds__(256, 3) void gemm_f32a(
    const float* __restrict__ Ag, const u16* __restrict__ Bg, u16* __restrict__ Cg,
    int K, int N, long sB0, long sC0)
{
    __shared__ float As[128 * 64];   // 32 KB
    __shared__ u16   Bs[128 * 64];   // 16 KB

    int z = blockIdx.z;
    const u16* B = Bg + (long)z * sB0;
    u16* Cu = Cg + (long)z * sC0;

    int tid  = threadIdx.x;
    int lane = tid & 63, wave = tid >> 6;
    int wm = wave & 1, wn = wave >> 1;
    int ln31 = lane & 31, khalf = lane >> 5;

    long m0 = (long)blockIdx.x * 128;
    long n0 = (long)blockIdx.y * 128;

    // A staging: 2048 16B chunks (4 f32); p -> row p>>4, slot p&15, q = slot^(row&15)
    long aOfs[8]; float* lA[8];
#pragma unroll
    for (int i = 0; i < 8; i++) {
        int p = tid + i * 256;
        int row = p >> 4, q = (p & 15) ^ (row & 15);
        aOfs[i] = (m0 + row) * (long)K + q * 4;
        lA[i] = As + p * 4;
    }
    // B staging: 1024 16B chunks (8 bf16); slot XOR as in gemm128
    long bOfs[4]; u16* lB[4];
#pragma unroll
    for (int i = 0; i < 4; i++) {
        int p = tid + i * 256;
        int row = p >> 3, q = (p & 7) ^ (row & 7);
        bOfs[i] = (n0 + row) * (long)K + q * 8;
        lB[i] = Bs + p * 8;
    }

    // fragment offsets: A needs f32 k in [h*16+khalf*8, +8) = chunks c0, c0+1
    int aoff[2][4][2], boff[2][4];
#pragma unroll
    for (int t = 0; t < 2; t++) {
        int ra = wm * 64 + t * 32 + ln31;
        int rb = wn * 64 + t * 32 + ln31;
#pragma unroll
        for (int h = 0; h < 4; h++) {
            int c0 = h * 4 + khalf * 2;
            aoff[t][h][0] = ra * 64 + ((c0 ^ (ra & 15)) * 4);
            aoff[t][h][1] = ra * 64 + (((c0 + 1) ^ (ra & 15)) * 4);
            boff[t][h] = rb * 64 + (((h * 2 + khalf) ^ (rb & 7)) * 8);
        }
    }

    f32x16 acc[2][2] = {};

    for (int k0 = 0; k0 < K; k0 += 64) {
#pragma unroll
        for (int i = 0; i < 8; i++) gl_lds16(Ag + aOfs[i] + k0, lA[i]);
#pragma unroll
        for (int i = 0; i < 4; i++) gl_lds16(B + bOfs[i] + k0, lB[i]);
        __syncthreads();

#pragma unroll
        for (int h = 0; h < 4; h++) {
            short8 af[2], bfr[2];
#pragma unroll
            for (int t = 0; t < 2; t++) {
                float4 v0 = *(const float4*)(As + aoff[t][h][0]);
                float4 v1 = *(const float4*)(As + aoff[t][h][1]);
                uint4 wv;
                wv.x = pkbf_rtz(v0.x, v0.y);
                wv.y = pkbf_rtz(v0.z, v0.w);
                wv.z = pkbf_rtz(v1.x, v1.y);
                wv.w = pkbf_rtz(v1.z, v1.w);
                af[t] = __builtin_bit_cast(short8, wv);
            }
#pragma unroll
            for (int t = 0; t < 2; t++) bfr[t] = *(const short8*)(Bs + boff[t][h]);
#pragma unroll
            for (int ti = 0; ti < 2; ti++)
#pragma unroll
                for (int tj = 0; tj < 2; tj++)
                    acc[ti][tj] = __builtin_amdgcn_mfma_f32_32x32x16_bf16(
                        af[ti], bfr[tj], acc[ti][tj], 0, 0, 0);
        }
        __syncthreads();
    }

    long crow = m0 + wm * 64 + 4 * khalf;
    long ccol = n0 + wn * 64 + ln31;
#pragma unroll
    for (int ti = 0; ti < 2; ti++)
#pragma unroll
        for (int tj = 0; tj < 2; tj++)
#pragma unroll
            for (int r = 0; r < 16; r++) {
                long row = crow + ti * 32 + (r & 3) + 8 * (r >> 2);
                long col = ccol + tj * 32;
                Cu[row * (long)N + col] = f2bf(acc[ti][tj][r]);
            }
}

// ---------------------------------------------------------------------------
// reductions
// ---------------------------------------------------------------------------
DEV float wave_red_max(float v) {
#pragma unroll
    for (int o = 32; o; o >>= 1) v = fmaxf(v, __shfl_xor(v, o));
    return v;
}
DEV float wave_red_sum(float v) {
#pragma unroll
    for (int o = 32; o; o >>= 1) v += __shfl_xor(v, o);
    return v;
}
// 4-wave (256-thread) block reductions
DEV float block_red_max(float v, float* sh) {
    v = wave_red_max(v);
    if ((threadIdx.x & 63) == 0) sh[threadIdx.x >> 6] = v;
    __syncthreads();
    v = fmaxf(fmaxf(sh[0], sh[1]), fmaxf(sh[2], sh[3]));
    __syncthreads();
    return v;
}
DEV float block_red_sum(float v, float* sh) {
    v = wave_red_sum(v);
    if ((threadIdx.x & 63) == 0) sh[threadIdx.x >> 6] = v;
    __syncthreads();
    v = (sh[0] + sh[1]) + (sh[2] + sh[3]);
    __syncthreads();
    return v;
}
// 2-wave (128-thread) block reductions
DEV float red2_max(float v, float* sh) {
    v = wave_red_max(v);
    if ((threadIdx.x & 63) == 0) sh[threadIdx.x >> 6] = v;
    __syncthreads();
    v = fmaxf(sh[0], sh[1]);
    __syncthreads();
    return v;
}
DEV float red2_sum(float v, float* sh) {
    v = wave_red_sum(v);
    if ((threadIdx.x & 63) == 0) sh[threadIdx.x >> 6] = v;
    __syncthreads();
    v = sh[0] + sh[1];
    __syncthreads();
    return v;
}

// ---------------------------------------------------------------------------
// Fused prep: flat grid, 256-thread blocks:
//   [0, 12288)          conv_y : yb = bf16(y); yT = bf16(y^T) via 32x32 tile
//   [12288, 13312)      pos    : P[n,:] = softmax(coords[n] @ pos_emb[n])
//   [13312, 13888)      prep_u : UTb = bf16(U^T), VT_s = bf16(S_s^2 * U)^T
// ---------------------------------------------------------------------------
__global__ __launch_bounds__(256) void k_prep_all(
    const float* __restrict__ y,
    const float* __restrict__ coords, const float* __restrict__ U,
    const float* __restrict__ S1, const float* __restrict__ S2,
    const float* __restrict__ pe,
    u16* __restrict__ yb, u16* __restrict__ yT,
    u16* __restrict__ UTb, u16* __restrict__ VT1, u16* __restrict__ VT2,
    float* __restrict__ P)
{
    __shared__ float shmem[32 * 33];
    int bid = blockIdx.x, tid = threadIdx.x;

    if (bid < 12288) {                         // ---- conv_y
        float (*tile)[33] = (float(*)[33])shmem;
        int b = bid / 768, rem = bid % 768;
        int d0 = (rem % 24) * 32, m0 = (rem / 24) * 32;
        int tx = tid & 31, ty = tid >> 5;
        const float* ybase = y + (long)b * NN * DD;
#pragma unroll
        for (int r = 0; r < 32; r += 8) {
            int m = m0 + ty + r, d = d0 + tx;
            float v = ybase[(long)m * DD + d];
            tile[ty + r][tx] = v;
            yb[(long)b * NN * DD + (long)m * DD + d] = f2bf(v);
        }
        __syncthreads();
#pragma unroll
        for (int r = 0; r < 32; r += 8) {
            int d = d0 + ty + r, m = m0 + tx;
            yT[(long)b * DD * NN + (long)d * NN + m] = f2bf(tile[tx][ty + r]);
        }
        return;
    }
    bid -= 12288;

    if (bid < 1024) {                          // ---- pos
        int n = bid, t = tid;
        float p6[6];
#pragma unroll
        for (int c = 0; c < 6; c++) p6[c] = pe[n * 6 + c];
        float v[4];
#pragma unroll
        for (int i = 0; i < 4; i++) {
            const float* cp = coords + ((long)n * NN + t * 4 + i) * 6;
            v[i] = p6[0]*cp[0] + p6[1]*cp[1] + p6[2]*cp[2]
                 + p6[3]*cp[3] + p6[4]*cp[4] + p6[5]*cp[5];
        }
        float mx = block_red_max(fmaxf(fmaxf(v[0], v[1]), fmaxf(v[2], v[3])), shmem);
        float e[4], s = 0.f;
#pragma unroll
        for (int i = 0; i < 4; i++) { e[i] = expf(v[i] - mx); s += e[i]; }
        float Z = block_red_sum(s, shmem);
        float inv = 1.f / Z;
        float4 o; o.x = e[0]*inv; o.y = e[1]*inv; o.z = e[2]*inv; o.w = e[3]*inv;
        *(float4*)(P + ((long)n << 10) + t * 4) = o;
        return;
    }
    bid -= 1024;

    {                                          // ---- prep_u (576 blocks)
        float (*tile)[33] = (float(*)[33])shmem;
        int i0 = (bid % 24) * 32, j0 = (bid / 24) * 32;
        int tx = tid & 31, ty = tid >> 5;
#pragma unroll
        for (int r = 0; r < 32; r += 8) {
            int i = i0 + ty + r, j = j0 + tx;
            tile[ty + r][tx] = U[(long)i * DD + j];
        }
        __syncthreads();
        float s1v = S1[i0 + tx];
        float s2v = S2[i0 + tx];
        s1v *= s1v; s2v *= s2v;
#pragma unroll
        for (int r = 0; r < 32; r += 8) {
            int j = j0 + ty + r, i = i0 + tx;
            float v = tile[tx][ty + r];   // U[i][j]
            UTb[(long)j * DD + i] = f2bf(v);
            VT1[(long)j * DD + i] = f2bf(s1v * v);
            VT2[(long)j * DD + i] = f2bf(s2v * v);
        }
    }
}

// ---------------------------------------------------------------------------
// Per (b,n) row: softmax both k, blend with pos, entropy, route, write heat
// and selected blended attn row (bf16 bits) IN-PLACE over S plane k=0.
// grid (B*N), block 128 (2 waves), 8 m per thread per plane, 16B loads.
// ---------------------------------------------------------------------------
__global__ __launch_bounds__(128) void k_route(
    u16* __restrict__ S, const float* __restrict__ P,
    const float* __restrict__ gating, const float* __restrict__ temp,
    float* __restrict__ heat)
{
    __shared__ float sh[2];
    int bn = blockIdx.x;
    int b = bn >> 10, n = bn & 1023, t = threadIdx.x;
    u16* s1p = S + ((long)(b * 2) << 20) + ((long)n << 10) + t * 8;
    u16* s2p = s1p + (1L << 20);
    const float* pp = P + ((long)n << 10) + t * 8;

    short8 r1 = *(const short8*)s1p;
    short8 r2 = *(const short8*)s2p;
    float4 pv0 = *(const float4*)pp;
    float4 pv1 = *(const float4*)(pp + 4);
    float s1[8], s2[8], p8[8];
#pragma unroll
    for (int i = 0; i < 8; i++) {
        s1[i] = h2f((u16)r1[i]);
        s2[i] = h2f((u16)r2[i]);
    }
    p8[0]=pv0.x; p8[1]=pv0.y; p8[2]=pv0.z; p8[3]=pv0.w;
    p8[4]=pv1.x; p8[5]=pv1.y; p8[6]=pv1.z; p8[7]=pv1.w;

    float m1 = s1[0], m2 = s2[0];
#pragma unroll
    for (int i = 1; i < 8; i++) { m1 = fmaxf(m1, s1[i]); m2 = fmaxf(m2, s2[i]); }
    float mx1 = red2_max(m1, sh);
    float mx2 = red2_max(m2, sh);

    float e1[8], e2[8], z1 = 0.f, z2 = 0.f;
#pragma unroll
    for (int i = 0; i < 8; i++) {
        e1[i] = expf(s1[i] - mx1); z1 += e1[i];
        e2[i] = expf(s2[i] - mx2); z2 += e2[i];
    }
    float Z1 = red2_sum(z1, sh);
    float Z2 = red2_sum(z2, sh);

    float g = 1.f / (1.f + expf(-gating[0]));
    float c1 = (1.f - g) / Z1, c2 = (1.f - g) / Z2;

    float a1[8], a2[8], hh1 = 0.f, hh2 = 0.f;
#pragma unroll
    for (int i = 0; i < 8; i++) {
        a1[i] = e1[i] * c1 + g * p8[i];
        a2[i] = e2[i] * c2 + g * p8[i];
        hh1 -= a1[i] * logf(a1[i] + 1e-8f);
        hh2 -= a2[i] * logf(a2[i] + 1e-8f);
    }
    float H1 = red2_sum(hh1, sh);
    float H2 = red2_sum(hh2, sh);

    float tv = temp[0];
    float hm0 = 2.f - 2.f / (1.f + expf(-tv * H1));
    float hm1 = 2.f - 2.f / (1.f + expf(-tv * H2));
    int ks = (hm0 >= hm1) ? 0 : 1;
    if (t == 0) heat[bn] = ks ? hm1 : hm0;

    short8 w;
#pragma unroll
    for (int i = 0; i < 8; i++) w[i] = (short)f2bf(ks ? a2[i] : a1[i]);
    *(short8*)s1p = w;   // attn_c (bf16 bits) over k=0 score plane
}

// ---------------------------------------------------------------------------
extern "C" void kernel_launch(void* const* d_in, const int* in_sizes, int n_in,
                              void* d_out, int out_size, void* d_ws, size_t ws_size,
                              hipStream_t stream)
{
    (void)in_sizes; (void)n_in; (void)out_size; (void)ws_size;
    const float* x      = (const float*)d_in[0];
    const float* y      = (const float*)d_in[1];
    const float* coords = (const float*)d_in[2];
    const float* U      = (const float*)d_in[3];
    const float* S1     = (const float*)d_in[4];
    const float* S2     = (const float*)d_in[5];
    const float* gating = (const float*)d_in[6];
    const float* temp   = (const float*)d_in[7];
    const float* pose   = (const float*)d_in[8];

    float* out  = (float*)d_out;
    float* heat = out + (long)BB * NN * DD;

    char* w = (char*)d_ws;
    u16* UTb = (u16*)w;  w += (long)DD * DD * 2;            //  1.125 MB
    u16* VT  = (u16*)w;  w += (long)2 * DD * DD * 2;        //  2.25 MB (VT1,VT2)
    u16* W2  = (u16*)w;  w += (long)2 * DD * DD * 2;        //  2.25 MB (W1,W2)
    u16* x12 = (u16*)w;  w += (long)2 * BB * NN * DD * 2;   // 48 MB
    u16* yb  = (u16*)w;  w += (long)BB * NN * DD * 2;       // 24 MB
    u16* yT  = (u16*)w;  w += (long)BB * DD * NN * 2;       // 24 MB
    u16* S   = (u16*)w;  w += (long)BB * 2 * NN * NN * 2;   // 64 MB
    float* P = (float*)w;                                   //  4 MB

    const long MBN = (long)BB * NN * DD;       // x1/x2 plane elements
    const long BND = (long)NN * DD;            // per-b x/y plane
    const long SPL = (long)NN * NN;            // score plane
    const long DSQ = (long)DD * DD;

    // fused prep: conv_y | pos | prep_u
    k_prep_all<<<dim3(13888), dim3(256), 0, stream>>>(
        y, coords, U, S1, S2, pose, yb, yT, UTb, VT, VT + DSQ, P);

    // W_s[i,j] = sum_t U[t,i] S_s[t]^2 U[t,j]  (NT: A=UTb, B=VT_s); z = s
    gemm128<0><<<dim3(DD / 128, DD / 128, 2), dim3(256), 0, stream>>>(
        UTb, VT, W2, DD, DD, 2,
        0L, 0L, DSQ, 0L, DSQ, 0L, 1.0f);

    // x12[s] = x (f32, staged direct) @ W_s  (W symmetric); z = s
    gemm_f32a<<<dim3(BB * NN / 128, DD / 128, 2), dim3(256), 0, stream>>>(
        x, W2, x12, DD, DD, DSQ, MBN);

    // S[b,k] = scale * x_k[b] @ y[b]^T   (C f16); z = b*2 + k
    gemm128<1><<<dim3(NN / 128, NN / 128, BB * 2), dim3(256), 0, stream>>>(
        x12, yb, S, DD, NN, 2,
        MBN, BND, 0L, BND, SPL, 2 * SPL, 0.036084391824351615f);

    // softmax + blend + entropy + route; attn_c (bf16) in-place at k=0 plane
    k_route<<<dim3(BB * NN), dim3(128), 0, stream>>>(S, P, gating, temp, heat);

    // out[b] = attn_c[b] @ y[b]   (A bf16 in S k=0 plane, B = yT bf16, C f32)
    gemm128<2><<<dim3(NN / 128, DD / 128, BB), dim3(256), 0, stream>>>(
        S, yT, out, NN, DD, 1,
        0L, 2 * SPL, 0L, BND, 0L, BND, 1.0f);
}